// Round 1
// baseline (1276.485 us; speedup 1.0000x reference)
//
#include <hip/hip_runtime.h>
#include <math.h>

#define N_NODES 20000
#define N_EDGES 320000
#define N_GRAPH 64
#define IN_DIM  512
#define HID     256
#define F2      512   // HEADS*HID
#define EPS_BN  1e-5f
#define SLOPE   0.2f

// ---------------- init: zero the ws regions that need it ----------------
__global__ void init_zero_kernel(int* counts, int* cursor, float* stats) {
    int i = blockIdx.x * blockDim.x + threadIdx.x;
    if (i < N_NODES) { counts[i] = 0; cursor[i] = 0; }
    if (i < 1024) stats[i] = 0.f;
}

// ---------------- tiled fp32 GEMM: C[N,M] = X[N,512] @ W[512,M] + bias --
// USE_BN: apply per-k scale/shift to X at load (folds BatchNorm into GEMM)
template <bool USE_BN>
__global__ __launch_bounds__(256) void gemm64(
    const float* __restrict__ X, const float* __restrict__ W,
    const float* __restrict__ bias, float* __restrict__ C,
    int Nrows, int M,
    const float* __restrict__ bscale, const float* __restrict__ bshift) {
    __shared__ float As[16][65];
    __shared__ float Bs[16][65];
    int tid = threadIdx.x;
    int row0 = blockIdx.x * 64;
    int col0 = blockIdx.y * 64;
    int tx = tid & 15, ty = tid >> 4;
    int a_m = tid >> 2;          // 0..63
    int a_k = (tid & 3) << 2;    // 0,4,8,12
    int b_n = tid & 63;
    int b_k0 = tid >> 6;         // 0..3
    float acc[4][4] = {};
    for (int k0 = 0; k0 < 512; k0 += 16) {
        int gr = row0 + a_m;
        float4 av = make_float4(0.f, 0.f, 0.f, 0.f);
        if (gr < Nrows) av = *(const float4*)(X + (size_t)gr * 512 + k0 + a_k);
        if (USE_BN) {
            av.x = av.x * bscale[k0 + a_k + 0] + bshift[k0 + a_k + 0];
            av.y = av.y * bscale[k0 + a_k + 1] + bshift[k0 + a_k + 1];
            av.z = av.z * bscale[k0 + a_k + 2] + bshift[k0 + a_k + 2];
            av.w = av.w * bscale[k0 + a_k + 3] + bshift[k0 + a_k + 3];
        }
        As[a_k + 0][a_m] = av.x;
        As[a_k + 1][a_m] = av.y;
        As[a_k + 2][a_m] = av.z;
        As[a_k + 3][a_m] = av.w;
#pragma unroll
        for (int j = 0; j < 4; j++) {
            int kk = b_k0 + j * 4;
            Bs[kk][b_n] = W[(size_t)(k0 + kk) * M + col0 + b_n];
        }
        __syncthreads();
#pragma unroll
        for (int kk = 0; kk < 16; kk++) {
            float a0 = As[kk][ty * 4 + 0], a1 = As[kk][ty * 4 + 1];
            float a2 = As[kk][ty * 4 + 2], a3 = As[kk][ty * 4 + 3];
            float b0 = Bs[kk][tx * 4 + 0], b1 = Bs[kk][tx * 4 + 1];
            float b2 = Bs[kk][tx * 4 + 2], b3 = Bs[kk][tx * 4 + 3];
            acc[0][0] += a0 * b0; acc[0][1] += a0 * b1; acc[0][2] += a0 * b2; acc[0][3] += a0 * b3;
            acc[1][0] += a1 * b0; acc[1][1] += a1 * b1; acc[1][2] += a1 * b2; acc[1][3] += a1 * b3;
            acc[2][0] += a2 * b0; acc[2][1] += a2 * b1; acc[2][2] += a2 * b2; acc[2][3] += a2 * b3;
            acc[3][0] += a3 * b0; acc[3][1] += a3 * b1; acc[3][2] += a3 * b2; acc[3][3] += a3 * b3;
        }
        __syncthreads();
    }
#pragma unroll
    for (int i = 0; i < 4; i++) {
        int r = row0 + ty * 4 + i;
        if (r < Nrows) {
#pragma unroll
            for (int j = 0; j < 4; j++) {
                int c = col0 + tx * 4 + j;
                C[(size_t)r * M + c] = acc[i][j] + bias[c];
            }
        }
    }
}

// ---------------- CSR build ----------------
__global__ void hist_kernel(const int* __restrict__ dst, int* __restrict__ counts) {
    int e = blockIdx.x * blockDim.x + threadIdx.x;
    if (e < N_EDGES) atomicAdd(&counts[dst[e]], 1);
}

__global__ __launch_bounds__(1024) void scan_kernel(const int* __restrict__ counts,
                                                    int* __restrict__ row_ptr) {
    __shared__ int buf[1024];
    __shared__ int carry;
    int tid = threadIdx.x;
    if (tid == 0) { carry = 0; row_ptr[0] = 0; }
    __syncthreads();
    for (int base = 0; base < N_NODES; base += 1024) {
        int v = (base + tid < N_NODES) ? counts[base + tid] : 0;
        buf[tid] = v;
        __syncthreads();
        for (int off = 1; off < 1024; off <<= 1) {
            int t = (tid >= off) ? buf[tid - off] : 0;
            __syncthreads();
            buf[tid] += t;
            __syncthreads();
        }
        if (base + tid < N_NODES) row_ptr[base + tid + 1] = carry + buf[tid];
        __syncthreads();
        if (tid == 0) carry += buf[1023];
        __syncthreads();
    }
}

__global__ void scatter_kernel(const int* __restrict__ dst, const int* __restrict__ row_ptr,
                               int* __restrict__ cursor, int* __restrict__ csr) {
    int e = blockIdx.x * blockDim.x + threadIdx.x;
    if (e < N_EDGES) {
        int d = dst[e];
        int pos = atomicAdd(&cursor[d], 1);
        csr[row_ptr[d] + pos] = e;
    }
}

// ---------------- edge scores: s[e][h] = exp(attn_h . leaky(fs[src]+fd[dst])) ----
__device__ __forceinline__ float lrelu(float x) { return x > 0.f ? x : SLOPE * x; }

__global__ __launch_bounds__(256) void edge_score_kernel(
    const float* __restrict__ FS, const float* __restrict__ FD,
    const int* __restrict__ src, const int* __restrict__ dst,
    const float* __restrict__ attn, float* __restrict__ sexp) {
    int e = blockIdx.x * 4 + (threadIdx.x >> 6);
    int lane = threadIdx.x & 63;
    if (e >= N_EDGES) return;
    int si = src[e], di = dst[e];
    const float4* fs = (const float4*)(FS + (size_t)si * F2);
    const float4* fd = (const float4*)(FD + (size_t)di * F2);
    const float4* at = (const float4*)attn;
    float4 a0 = fs[lane], d0 = fd[lane], w0 = at[lane];          // head 0
    float4 a1 = fs[64 + lane], d1 = fd[64 + lane], w1 = at[64 + lane];  // head 1
    float p0 = lrelu(a0.x + d0.x) * w0.x + lrelu(a0.y + d0.y) * w0.y +
               lrelu(a0.z + d0.z) * w0.z + lrelu(a0.w + d0.w) * w0.w;
    float p1 = lrelu(a1.x + d1.x) * w1.x + lrelu(a1.y + d1.y) * w1.y +
               lrelu(a1.z + d1.z) * w1.z + lrelu(a1.w + d1.w) * w1.w;
#pragma unroll
    for (int off = 32; off > 0; off >>= 1) {
        p0 += __shfl_down(p0, off, 64);
        p1 += __shfl_down(p1, off, 64);
    }
    if (lane == 0) {
        sexp[2 * e] = expf(p0);
        sexp[2 * e + 1] = expf(p1);
    }
}

// ---------------- per-dst aggregation + ELU + skip (in-place on h1) -----
__global__ __launch_bounds__(256) void aggregate_kernel(
    const float* __restrict__ FS, const float* __restrict__ sexp,
    const int* __restrict__ csr, const int* __restrict__ row_ptr,
    const int* __restrict__ src, float* __restrict__ h1) {
    int n = blockIdx.x;
    int tid = threadIdx.x;
    int beg = row_ptr[n], end = row_ptr[n + 1];
    __shared__ float red[256];
    __shared__ float al0[256], al1[256];
    __shared__ int esrc[256];

    float d0 = 0.f, d1 = 0.f;
    for (int i = beg + tid; i < end; i += 256) {
        int eid = csr[i];
        d0 += sexp[2 * eid];
        d1 += sexp[2 * eid + 1];
    }
    red[tid] = d0; __syncthreads();
    for (int off = 128; off > 0; off >>= 1) { if (tid < off) red[tid] += red[tid + off]; __syncthreads(); }
    float den0 = red[0];
    __syncthreads();
    red[tid] = d1; __syncthreads();
    for (int off = 128; off > 0; off >>= 1) { if (tid < off) red[tid] += red[tid + off]; __syncthreads(); }
    float den1 = red[0];
    __syncthreads();
    float inv0 = den0 > 0.f ? 1.f / den0 : 0.f;
    float inv1 = den1 > 0.f ? 1.f / den1 : 0.f;

    float acc0 = 0.f, acc1 = 0.f;
    for (int cbeg = beg; cbeg < end; cbeg += 256) {
        int cnt = min(256, end - cbeg);
        if (tid < cnt) {
            int eid = csr[cbeg + tid];
            esrc[tid] = src[eid];
            al0[tid] = sexp[2 * eid] * inv0;
            al1[tid] = sexp[2 * eid + 1] * inv1;
        }
        __syncthreads();
        for (int i = 0; i < cnt; i++) {
            const float* fr = FS + (size_t)esrc[i] * F2;
            acc0 += al0[i] * fr[tid];
            acc1 += al1[i] * fr[256 + tid];
        }
        __syncthreads();
    }
    // ELU + skip (skip GEMM already wrote into h1)
    float e0 = acc0 > 0.f ? acc0 : expm1f(acc0);
    float e1 = acc1 > 0.f ? acc1 : expm1f(acc1);
    size_t base = (size_t)n * F2;
    h1[base + tid] = e0 + h1[base + tid];
    h1[base + 256 + tid] = e1 + h1[base + 256 + tid];
}

// ---------------- BatchNorm stats ----------------
__global__ __launch_bounds__(256) void bn_stats_kernel(const float* __restrict__ h1,
                                                       float* __restrict__ stats,
                                                       int rows_per_block) {
    int tid = threadIdx.x;
    int r0 = blockIdx.x * rows_per_block;
    int r1 = min(r0 + rows_per_block, N_NODES);
    float s0 = 0.f, q0 = 0.f, s1 = 0.f, q1 = 0.f;
    for (int r = r0; r < r1; r++) {
        float a = h1[(size_t)r * F2 + tid];
        float b = h1[(size_t)r * F2 + 256 + tid];
        s0 += a; q0 += a * a;
        s1 += b; q1 += b * b;
    }
    atomicAdd(&stats[tid], s0);
    atomicAdd(&stats[256 + tid], s1);
    atomicAdd(&stats[512 + tid], q0);
    atomicAdd(&stats[512 + 256 + tid], q1);
}

__global__ void bn_finalize_kernel(const float* __restrict__ stats,
                                   const float* __restrict__ gamma,
                                   const float* __restrict__ beta,
                                   float* __restrict__ bscale, float* __restrict__ bshift) {
    int c = threadIdx.x;  // 512 threads
    float mu = stats[c] / (float)N_NODES;
    float var = stats[512 + c] / (float)N_NODES - mu * mu;
    float sc = gamma[c] * rsqrtf(var + EPS_BN);
    bscale[c] = sc;
    bshift[c] = beta[c] - mu * sc;
}

// ---------------- gate scores ----------------
__global__ __launch_bounds__(256) void gate_kernel(const float* __restrict__ hr,
                                                   const float* __restrict__ wg,
                                                   const float* __restrict__ bg,
                                                   float* __restrict__ gate) {
    int n = blockIdx.x * 4 + (threadIdx.x >> 6);
    int lane = threadIdx.x & 63;
    const float4* row = (const float4*)(hr + (size_t)n * HID);
    const float4* w = (const float4*)wg;
    float4 a = row[lane], b = w[lane];
    float p = a.x * b.x + a.y * b.y + a.z * b.z + a.w * b.w;
#pragma unroll
    for (int off = 32; off > 0; off >>= 1) p += __shfl_down(p, off, 64);
    if (lane == 0) gate[n] = p + bg[0];
}

// ---------------- per-graph attention pooling ----------------
__device__ __forceinline__ int lower_bound_dev(const int* a, int n, int v) {
    int lo = 0, hi = n;
    while (lo < hi) {
        int mid = (lo + hi) >> 1;
        if (a[mid] < v) lo = mid + 1; else hi = mid;
    }
    return lo;
}

__global__ __launch_bounds__(256) void pool_kernel(const float* __restrict__ hr,
                                                   const float* __restrict__ gate,
                                                   const int* __restrict__ gids,
                                                   float* __restrict__ h_g) {
    int g = blockIdx.x;
    int tid = threadIdx.x;
    int start = lower_bound_dev(gids, N_NODES, g);
    int end = lower_bound_dev(gids, N_NODES, g + 1);
    __shared__ float red[256];
    __shared__ float wa[256];
    if (start >= end) { h_g[g * HID + tid] = 0.f; return; }
    float m = -3.4e38f;
    for (int i = start + tid; i < end; i += 256) m = fmaxf(m, gate[i]);
    red[tid] = m; __syncthreads();
    for (int off = 128; off > 0; off >>= 1) { if (tid < off) red[tid] = fmaxf(red[tid], red[tid + off]); __syncthreads(); }
    float gmax = red[0];
    __syncthreads();
    float se = 0.f;
    for (int i = start + tid; i < end; i += 256) se += expf(gate[i] - gmax);
    red[tid] = se; __syncthreads();
    for (int off = 128; off > 0; off >>= 1) { if (tid < off) red[tid] += red[tid + off]; __syncthreads(); }
    float ssum = red[0];
    __syncthreads();
    float acc = 0.f;
    for (int cbeg = start; cbeg < end; cbeg += 256) {
        int cnt = min(256, end - cbeg);
        if (tid < cnt) wa[tid] = expf(gate[cbeg + tid] - gmax);
        __syncthreads();
        for (int i = 0; i < cnt; i++) acc += wa[i] * hr[(size_t)(cbeg + i) * HID + tid];
        __syncthreads();
    }
    h_g[g * HID + tid] = acc / ssum;
}

// ---------------- classifier ----------------
__global__ __launch_bounds__(128) void classifier_kernel(
    const float* __restrict__ h_g, const float* __restrict__ W1, const float* __restrict__ b1,
    const float* __restrict__ W2, const float* __restrict__ b2, float* __restrict__ out) {
    int g = blockIdx.x;
    int tid = threadIdx.x;  // 128
    __shared__ float hg[256];
    __shared__ float z1[128];
    hg[tid] = h_g[g * HID + tid];
    hg[tid + 128] = h_g[g * HID + tid + 128];
    __syncthreads();
    float a = b1[tid];
#pragma unroll 8
    for (int k = 0; k < 256; k++) a += hg[k] * W1[k * 128 + tid];
    z1[tid] = a > 0.f ? a : 0.f;
    __syncthreads();
    if (tid < 10) {
        float o = b2[tid];
#pragma unroll 8
        for (int j = 0; j < 128; j++) o += z1[j] * W2[j * 10 + tid];
        out[g * 10 + tid] = o;
    }
}

// ---------------- launcher ----------------
extern "C" void kernel_launch(void* const* d_in, const int* in_sizes, int n_in,
                              void* d_out, int out_size, void* d_ws, size_t ws_size,
                              hipStream_t stream) {
    const float* feat   = (const float*)d_in[0];
    const int*   src    = (const int*)d_in[1];
    const int*   dst    = (const int*)d_in[2];
    const int*   gids   = (const int*)d_in[3];
    const float* W_src  = (const float*)d_in[4];
    const float* b_src  = (const float*)d_in[5];
    const float* W_dst  = (const float*)d_in[6];
    const float* b_dst  = (const float*)d_in[7];
    const float* attn   = (const float*)d_in[8];
    const float* W_skip = (const float*)d_in[9];
    const float* b_skip = (const float*)d_in[10];
    const float* gamma  = (const float*)d_in[11];
    const float* beta   = (const float*)d_in[12];
    const float* W_red  = (const float*)d_in[13];
    const float* b_red  = (const float*)d_in[14];
    const float* w_gate = (const float*)d_in[15];
    const float* b_gate = (const float*)d_in[16];
    const float* W1     = (const float*)d_in[17];
    const float* b1     = (const float*)d_in[18];
    const float* W2     = (const float*)d_in[19];
    const float* b2     = (const float*)d_in[20];
    float* out = (float*)d_out;

    char* p = (char*)d_ws;
    auto alloc = [&](size_t bytes) -> char* {
        char* r = p;
        p += (bytes + 255) & ~(size_t)255;
        return r;
    };
    float* FS       = (float*)alloc((size_t)N_NODES * F2 * 4);
    float* FD       = (float*)alloc((size_t)N_NODES * F2 * 4);
    float* h1       = (float*)alloc((size_t)N_NODES * F2 * 4);   // skip lands here, then elu(gat)+skip
    float* hr       = (float*)alloc((size_t)N_NODES * HID * 4);
    float* sexp     = (float*)alloc((size_t)N_EDGES * 2 * 4);
    float* gate     = (float*)alloc((size_t)N_NODES * 4);
    float* stats    = (float*)alloc(1024 * 4);
    float* bn_scale = (float*)alloc(512 * 4);
    float* bn_shift = (float*)alloc(512 * 4);
    float* h_g      = (float*)alloc((size_t)N_GRAPH * HID * 4);
    int* counts     = (int*)alloc((size_t)N_NODES * 4);
    int* row_ptr    = (int*)alloc((size_t)(N_NODES + 1) * 4);
    int* cursor     = (int*)alloc((size_t)N_NODES * 4);
    int* csr        = (int*)alloc((size_t)N_EDGES * 4);
    (void)ws_size; (void)in_sizes; (void)n_in; (void)out_size;

    // 1. init
    init_zero_kernel<<<(N_NODES + 255) / 256, 256, 0, stream>>>(counts, cursor, stats);

    // 2-4. fs, fd, skip GEMMs
    dim3 gemm_grid((N_NODES + 63) / 64, F2 / 64);
    gemm64<false><<<gemm_grid, 256, 0, stream>>>(feat, W_src, b_src, FS, N_NODES, F2, nullptr, nullptr);
    gemm64<false><<<gemm_grid, 256, 0, stream>>>(feat, W_dst, b_dst, FD, N_NODES, F2, nullptr, nullptr);
    gemm64<false><<<gemm_grid, 256, 0, stream>>>(feat, W_skip, b_skip, h1, N_NODES, F2, nullptr, nullptr);

    // 5-7. CSR by dst
    hist_kernel<<<(N_EDGES + 255) / 256, 256, 0, stream>>>(dst, counts);
    scan_kernel<<<1, 1024, 0, stream>>>(counts, row_ptr);
    scatter_kernel<<<(N_EDGES + 255) / 256, 256, 0, stream>>>(dst, row_ptr, cursor, csr);

    // 8. edge scores (softmax numerator; shift-invariance => no max pass needed)
    edge_score_kernel<<<N_EDGES / 4, 256, 0, stream>>>(FS, FD, src, dst, attn, sexp);

    // 9. per-dst aggregation + ELU + skip
    aggregate_kernel<<<N_NODES, 256, 0, stream>>>(FS, sexp, csr, row_ptr, src, h1);

    // 10-11. BatchNorm stats -> fold into scale/shift
    bn_stats_kernel<<<250, 256, 0, stream>>>(h1, stats, 80);
    bn_finalize_kernel<<<1, 512, 0, stream>>>(stats, gamma, beta, bn_scale, bn_shift);

    // 12. hr = BN(h1) @ W_red + b_red  (BN folded into A-load)
    dim3 red_grid((N_NODES + 63) / 64, HID / 64);
    gemm64<true><<<red_grid, 256, 0, stream>>>(h1, W_red, b_red, hr, N_NODES, HID, bn_scale, bn_shift);

    // 13. gate
    gate_kernel<<<N_NODES / 4, 256, 0, stream>>>(hr, w_gate, b_gate, gate);

    // 14. per-graph pooling
    pool_kernel<<<N_GRAPH, 256, 0, stream>>>(hr, gate, gids, h_g);

    // 15. classifier
    classifier_kernel<<<N_GRAPH, 128, 0, stream>>>(h_g, W1, b1, W2, b2, out);
}

// Round 2
// 1052.183 us; speedup vs baseline: 1.2132x; 1.2132x over previous
//
#include <hip/hip_runtime.h>
#include <math.h>

#define N_NODES 20000
#define N_EDGES 320000
#define N_GRAPH 64
#define IN_DIM  512
#define HID     256
#define F2      512   // HEADS*HID
#define EPS_BN  1e-5f
#define SLOPE   0.2f

// ---------------- init: zero the ws regions that need it ----------------
__global__ void init_zero_kernel(int* counts, int* cursor, float* stats) {
    int i = blockIdx.x * blockDim.x + threadIdx.x;
    if (i < N_NODES) { counts[i] = 0; cursor[i] = 0; }
    if (i < 1024) stats[i] = 0.f;
}

// ---------------- tiled fp32 GEMM: C[N,M] = X[N,512] @ W[512,M] + bias --
// 128x128 tile, BK=16, 8x8 microtile (as 2x2 of float4 halves 64 apart).
// All LDS reads are ds_read_b128; staging writes are <=2-way conflicts (free).
// USE_BN: apply per-k scale/shift to X at load (folds BatchNorm into GEMM).
template <bool USE_BN>
__global__ __launch_bounds__(256) void gemm128(
    const float* __restrict__ X, const float* __restrict__ W,
    const float* __restrict__ bias, float* __restrict__ C,
    int Nrows, int M,
    const float* __restrict__ bscale, const float* __restrict__ bshift) {
    __shared__ float As[16][132];
    __shared__ float Bs[16][132];
    int tid = threadIdx.x;
    int row0 = blockIdx.x * 128;
    int col0 = blockIdx.y * 128;
    int tx = tid & 15, ty = tid >> 4;

    // staging index maps (two float4 chunks per thread for each of A,B)
    int f1 = tid + 256;
    int am0 = tid >> 2, ak0 = (tid & 3) << 2;   // A chunk 0: row am0, k ak0..+3
    int am1 = f1 >> 2;                           // A chunk 1: row am1 (=64+am0'), same ak
    int bk0 = tid >> 5, bn0 = (tid & 31) << 2;  // B chunk 0: k-row bk0 (0..7)
    int bk1 = f1 >> 5;                           // B chunk 1: k-row 8..15

    float acc[8][8];
#pragma unroll
    for (int i = 0; i < 8; i++)
#pragma unroll
        for (int j = 0; j < 8; j++) acc[i][j] = 0.f;

    for (int k0 = 0; k0 < 512; k0 += 16) {
        // ---- stage A (with optional BN fold) ----
        float4 av0 = make_float4(0.f, 0.f, 0.f, 0.f);
        float4 av1 = make_float4(0.f, 0.f, 0.f, 0.f);
        int gr0 = row0 + am0, gr1 = row0 + am1;
        if (gr0 < Nrows) av0 = *(const float4*)(X + (size_t)gr0 * 512 + k0 + ak0);
        if (gr1 < Nrows) av1 = *(const float4*)(X + (size_t)gr1 * 512 + k0 + ak0);
        if (USE_BN) {
            float s0 = bscale[k0 + ak0 + 0], h0 = bshift[k0 + ak0 + 0];
            float s1 = bscale[k0 + ak0 + 1], h1 = bshift[k0 + ak0 + 1];
            float s2 = bscale[k0 + ak0 + 2], h2 = bshift[k0 + ak0 + 2];
            float s3 = bscale[k0 + ak0 + 3], h3 = bshift[k0 + ak0 + 3];
            av0.x = av0.x * s0 + h0; av0.y = av0.y * s1 + h1;
            av0.z = av0.z * s2 + h2; av0.w = av0.w * s3 + h3;
            av1.x = av1.x * s0 + h0; av1.y = av1.y * s1 + h1;
            av1.z = av1.z * s2 + h2; av1.w = av1.w * s3 + h3;
        }
        // ---- stage B (direct float4 copy, layout matches global) ----
        float4 bv0 = *(const float4*)(W + (size_t)(k0 + bk0) * M + col0 + bn0);
        float4 bv1 = *(const float4*)(W + (size_t)(k0 + bk1) * M + col0 + bn0);

        __syncthreads();  // protect previous iteration's reads
        As[ak0 + 0][am0] = av0.x; As[ak0 + 1][am0] = av0.y;
        As[ak0 + 2][am0] = av0.z; As[ak0 + 3][am0] = av0.w;
        As[ak0 + 0][am1] = av1.x; As[ak0 + 1][am1] = av1.y;
        As[ak0 + 2][am1] = av1.z; As[ak0 + 3][am1] = av1.w;
        *(float4*)&Bs[bk0][bn0] = bv0;
        *(float4*)&Bs[bk1][bn0] = bv1;
        __syncthreads();

#pragma unroll
        for (int kk = 0; kk < 16; kk++) {
            float a[8], b[8];
            *(float4*)&a[0] = *(const float4*)&As[kk][ty * 4];
            *(float4*)&a[4] = *(const float4*)&As[kk][64 + ty * 4];
            *(float4*)&b[0] = *(const float4*)&Bs[kk][tx * 4];
            *(float4*)&b[4] = *(const float4*)&Bs[kk][64 + tx * 4];
#pragma unroll
            for (int i = 0; i < 8; i++)
#pragma unroll
                for (int j = 0; j < 8; j++) acc[i][j] += a[i] * b[j];
        }
    }

    // ---- epilogue: bias + store (two float4 per row-part) ----
    float blo[4], bhi[4];
#pragma unroll
    for (int j = 0; j < 4; j++) {
        blo[j] = bias[col0 + tx * 4 + j];
        bhi[j] = bias[col0 + 64 + tx * 4 + j];
    }
#pragma unroll
    for (int ih = 0; ih < 2; ih++) {
#pragma unroll
        for (int i = 0; i < 4; i++) {
            int r = row0 + ih * 64 + ty * 4 + i;
            if (r < Nrows) {
                float4 v;
                v.x = acc[ih * 4 + i][0] + blo[0];
                v.y = acc[ih * 4 + i][1] + blo[1];
                v.z = acc[ih * 4 + i][2] + blo[2];
                v.w = acc[ih * 4 + i][3] + blo[3];
                *(float4*)(C + (size_t)r * M + col0 + tx * 4) = v;
                v.x = acc[ih * 4 + i][4] + bhi[0];
                v.y = acc[ih * 4 + i][5] + bhi[1];
                v.z = acc[ih * 4 + i][6] + bhi[2];
                v.w = acc[ih * 4 + i][7] + bhi[3];
                *(float4*)(C + (size_t)r * M + col0 + 64 + tx * 4) = v;
            }
        }
    }
}

// ---------------- CSR build ----------------
__global__ void hist_kernel(const int* __restrict__ dst, int* __restrict__ counts) {
    int e = blockIdx.x * blockDim.x + threadIdx.x;
    if (e < N_EDGES) atomicAdd(&counts[dst[e]], 1);
}

__global__ __launch_bounds__(1024) void scan_kernel(const int* __restrict__ counts,
                                                    int* __restrict__ row_ptr) {
    __shared__ int buf[1024];
    __shared__ int carry;
    int tid = threadIdx.x;
    if (tid == 0) { carry = 0; row_ptr[0] = 0; }
    __syncthreads();
    for (int base = 0; base < N_NODES; base += 1024) {
        int v = (base + tid < N_NODES) ? counts[base + tid] : 0;
        buf[tid] = v;
        __syncthreads();
        for (int off = 1; off < 1024; off <<= 1) {
            int t = (tid >= off) ? buf[tid - off] : 0;
            __syncthreads();
            buf[tid] += t;
            __syncthreads();
        }
        if (base + tid < N_NODES) row_ptr[base + tid + 1] = carry + buf[tid];
        __syncthreads();
        if (tid == 0) carry += buf[1023];
        __syncthreads();
    }
}

__global__ void scatter_kernel(const int* __restrict__ dst, const int* __restrict__ row_ptr,
                               int* __restrict__ cursor, int* __restrict__ csr) {
    int e = blockIdx.x * blockDim.x + threadIdx.x;
    if (e < N_EDGES) {
        int d = dst[e];
        int pos = atomicAdd(&cursor[d], 1);
        csr[row_ptr[d] + pos] = e;
    }
}

// ---------------- edge scores: s[e][h] = exp(attn_h . leaky(fs[src]+fd[dst])) ----
__device__ __forceinline__ float lrelu(float x) { return x > 0.f ? x : SLOPE * x; }

__global__ __launch_bounds__(256) void edge_score_kernel(
    const float* __restrict__ FS, const float* __restrict__ FD,
    const int* __restrict__ src, const int* __restrict__ dst,
    const float* __restrict__ attn, float* __restrict__ sexp) {
    int e = blockIdx.x * 4 + (threadIdx.x >> 6);
    int lane = threadIdx.x & 63;
    if (e >= N_EDGES) return;
    int si = src[e], di = dst[e];
    const float4* fs = (const float4*)(FS + (size_t)si * F2);
    const float4* fd = (const float4*)(FD + (size_t)di * F2);
    const float4* at = (const float4*)attn;
    float4 a0 = fs[lane], d0 = fd[lane], w0 = at[lane];          // head 0
    float4 a1 = fs[64 + lane], d1 = fd[64 + lane], w1 = at[64 + lane];  // head 1
    float p0 = lrelu(a0.x + d0.x) * w0.x + lrelu(a0.y + d0.y) * w0.y +
               lrelu(a0.z + d0.z) * w0.z + lrelu(a0.w + d0.w) * w0.w;
    float p1 = lrelu(a1.x + d1.x) * w1.x + lrelu(a1.y + d1.y) * w1.y +
               lrelu(a1.z + d1.z) * w1.z + lrelu(a1.w + d1.w) * w1.w;
#pragma unroll
    for (int off = 32; off > 0; off >>= 1) {
        p0 += __shfl_down(p0, off, 64);
        p1 += __shfl_down(p1, off, 64);
    }
    if (lane == 0) {
        sexp[2 * e] = expf(p0);
        sexp[2 * e + 1] = expf(p1);
    }
}

// ---------------- per-dst aggregation + ELU + skip (in-place on h1) -----
__global__ __launch_bounds__(256) void aggregate_kernel(
    const float* __restrict__ FS, const float* __restrict__ sexp,
    const int* __restrict__ csr, const int* __restrict__ row_ptr,
    const int* __restrict__ src, float* __restrict__ h1) {
    int n = blockIdx.x;
    int tid = threadIdx.x;
    int beg = row_ptr[n], end = row_ptr[n + 1];
    __shared__ float red[256];
    __shared__ float al0[256], al1[256];
    __shared__ int esrc[256];

    float d0 = 0.f, d1 = 0.f;
    for (int i = beg + tid; i < end; i += 256) {
        int eid = csr[i];
        d0 += sexp[2 * eid];
        d1 += sexp[2 * eid + 1];
    }
    red[tid] = d0; __syncthreads();
    for (int off = 128; off > 0; off >>= 1) { if (tid < off) red[tid] += red[tid + off]; __syncthreads(); }
    float den0 = red[0];
    __syncthreads();
    red[tid] = d1; __syncthreads();
    for (int off = 128; off > 0; off >>= 1) { if (tid < off) red[tid] += red[tid + off]; __syncthreads(); }
    float den1 = red[0];
    __syncthreads();
    float inv0 = den0 > 0.f ? 1.f / den0 : 0.f;
    float inv1 = den1 > 0.f ? 1.f / den1 : 0.f;

    float acc0 = 0.f, acc1 = 0.f;
    for (int cbeg = beg; cbeg < end; cbeg += 256) {
        int cnt = min(256, end - cbeg);
        if (tid < cnt) {
            int eid = csr[cbeg + tid];
            esrc[tid] = src[eid];
            al0[tid] = sexp[2 * eid] * inv0;
            al1[tid] = sexp[2 * eid + 1] * inv1;
        }
        __syncthreads();
        for (int i = 0; i < cnt; i++) {
            const float* fr = FS + (size_t)esrc[i] * F2;
            acc0 += al0[i] * fr[tid];
            acc1 += al1[i] * fr[256 + tid];
        }
        __syncthreads();
    }
    // ELU + skip (skip GEMM already wrote into h1)
    float e0 = acc0 > 0.f ? acc0 : expm1f(acc0);
    float e1 = acc1 > 0.f ? acc1 : expm1f(acc1);
    size_t base = (size_t)n * F2;
    h1[base + tid] = e0 + h1[base + tid];
    h1[base + 256 + tid] = e1 + h1[base + 256 + tid];
}

// ---------------- BatchNorm stats ----------------
__global__ __launch_bounds__(256) void bn_stats_kernel(const float* __restrict__ h1,
                                                       float* __restrict__ stats,
                                                       int rows_per_block) {
    int tid = threadIdx.x;
    int r0 = blockIdx.x * rows_per_block;
    int r1 = min(r0 + rows_per_block, N_NODES);
    float s0 = 0.f, q0 = 0.f, s1 = 0.f, q1 = 0.f;
    for (int r = r0; r < r1; r++) {
        float a = h1[(size_t)r * F2 + tid];
        float b = h1[(size_t)r * F2 + 256 + tid];
        s0 += a; q0 += a * a;
        s1 += b; q1 += b * b;
    }
    atomicAdd(&stats[tid], s0);
    atomicAdd(&stats[256 + tid], s1);
    atomicAdd(&stats[512 + tid], q0);
    atomicAdd(&stats[512 + 256 + tid], q1);
}

__global__ void bn_finalize_kernel(const float* __restrict__ stats,
                                   const float* __restrict__ gamma,
                                   const float* __restrict__ beta,
                                   float* __restrict__ bscale, float* __restrict__ bshift) {
    int c = threadIdx.x;  // 512 threads
    float mu = stats[c] / (float)N_NODES;
    float var = stats[512 + c] / (float)N_NODES - mu * mu;
    float sc = gamma[c] * rsqrtf(var + EPS_BN);
    bscale[c] = sc;
    bshift[c] = beta[c] - mu * sc;
}

// ---------------- gate scores ----------------
__global__ __launch_bounds__(256) void gate_kernel(const float* __restrict__ hr,
                                                   const float* __restrict__ wg,
                                                   const float* __restrict__ bg,
                                                   float* __restrict__ gate) {
    int n = blockIdx.x * 4 + (threadIdx.x >> 6);
    int lane = threadIdx.x & 63;
    const float4* row = (const float4*)(hr + (size_t)n * HID);
    const float4* w = (const float4*)wg;
    float4 a = row[lane], b = w[lane];
    float p = a.x * b.x + a.y * b.y + a.z * b.z + a.w * b.w;
#pragma unroll
    for (int off = 32; off > 0; off >>= 1) p += __shfl_down(p, off, 64);
    if (lane == 0) gate[n] = p + bg[0];
}

// ---------------- per-graph attention pooling ----------------
__device__ __forceinline__ int lower_bound_dev(const int* a, int n, int v) {
    int lo = 0, hi = n;
    while (lo < hi) {
        int mid = (lo + hi) >> 1;
        if (a[mid] < v) lo = mid + 1; else hi = mid;
    }
    return lo;
}

__global__ __launch_bounds__(256) void pool_kernel(const float* __restrict__ hr,
                                                   const float* __restrict__ gate,
                                                   const int* __restrict__ gids,
                                                   float* __restrict__ h_g) {
    int g = blockIdx.x;
    int tid = threadIdx.x;
    int start = lower_bound_dev(gids, N_NODES, g);
    int end = lower_bound_dev(gids, N_NODES, g + 1);
    __shared__ float red[256];
    __shared__ float wa[256];
    if (start >= end) { h_g[g * HID + tid] = 0.f; return; }
    float m = -3.4e38f;
    for (int i = start + tid; i < end; i += 256) m = fmaxf(m, gate[i]);
    red[tid] = m; __syncthreads();
    for (int off = 128; off > 0; off >>= 1) { if (tid < off) red[tid] = fmaxf(red[tid], red[tid + off]); __syncthreads(); }
    float gmax = red[0];
    __syncthreads();
    float se = 0.f;
    for (int i = start + tid; i < end; i += 256) se += expf(gate[i] - gmax);
    red[tid] = se; __syncthreads();
    for (int off = 128; off > 0; off >>= 1) { if (tid < off) red[tid] += red[tid + off]; __syncthreads(); }
    float ssum = red[0];
    __syncthreads();
    float acc = 0.f;
    for (int cbeg = start; cbeg < end; cbeg += 256) {
        int cnt = min(256, end - cbeg);
        if (tid < cnt) wa[tid] = expf(gate[cbeg + tid] - gmax);
        __syncthreads();
        for (int i = 0; i < cnt; i++) acc += wa[i] * hr[(size_t)(cbeg + i) * HID + tid];
        __syncthreads();
    }
    h_g[g * HID + tid] = acc / ssum;
}

// ---------------- classifier ----------------
__global__ __launch_bounds__(128) void classifier_kernel(
    const float* __restrict__ h_g, const float* __restrict__ W1, const float* __restrict__ b1,
    const float* __restrict__ W2, const float* __restrict__ b2, float* __restrict__ out) {
    int g = blockIdx.x;
    int tid = threadIdx.x;  // 128
    __shared__ float hg[256];
    __shared__ float z1[128];
    hg[tid] = h_g[g * HID + tid];
    hg[tid + 128] = h_g[g * HID + tid + 128];
    __syncthreads();
    float a = b1[tid];
#pragma unroll 8
    for (int k = 0; k < 256; k++) a += hg[k] * W1[k * 128 + tid];
    z1[tid] = a > 0.f ? a : 0.f;
    __syncthreads();
    if (tid < 10) {
        float o = b2[tid];
#pragma unroll 8
        for (int j = 0; j < 128; j++) o += z1[j] * W2[j * 10 + tid];
        out[g * 10 + tid] = o;
    }
}

// ---------------- launcher ----------------
extern "C" void kernel_launch(void* const* d_in, const int* in_sizes, int n_in,
                              void* d_out, int out_size, void* d_ws, size_t ws_size,
                              hipStream_t stream) {
    const float* feat   = (const float*)d_in[0];
    const int*   src    = (const int*)d_in[1];
    const int*   dst    = (const int*)d_in[2];
    const int*   gids   = (const int*)d_in[3];
    const float* W_src  = (const float*)d_in[4];
    const float* b_src  = (const float*)d_in[5];
    const float* W_dst  = (const float*)d_in[6];
    const float* b_dst  = (const float*)d_in[7];
    const float* attn   = (const float*)d_in[8];
    const float* W_skip = (const float*)d_in[9];
    const float* b_skip = (const float*)d_in[10];
    const float* gamma  = (const float*)d_in[11];
    const float* beta   = (const float*)d_in[12];
    const float* W_red  = (const float*)d_in[13];
    const float* b_red  = (const float*)d_in[14];
    const float* w_gate = (const float*)d_in[15];
    const float* b_gate = (const float*)d_in[16];
    const float* W1     = (const float*)d_in[17];
    const float* b1     = (const float*)d_in[18];
    const float* W2     = (const float*)d_in[19];
    const float* b2     = (const float*)d_in[20];
    float* out = (float*)d_out;

    char* p = (char*)d_ws;
    auto alloc = [&](size_t bytes) -> char* {
        char* r = p;
        p += (bytes + 255) & ~(size_t)255;
        return r;
    };
    float* FS       = (float*)alloc((size_t)N_NODES * F2 * 4);
    float* FD       = (float*)alloc((size_t)N_NODES * F2 * 4);
    float* h1       = (float*)alloc((size_t)N_NODES * F2 * 4);   // skip lands here, then elu(gat)+skip
    float* hr       = (float*)alloc((size_t)N_NODES * HID * 4);
    float* sexp     = (float*)alloc((size_t)N_EDGES * 2 * 4);
    float* gate     = (float*)alloc((size_t)N_NODES * 4);
    float* stats    = (float*)alloc(1024 * 4);
    float* bn_scale = (float*)alloc(512 * 4);
    float* bn_shift = (float*)alloc(512 * 4);
    float* h_g      = (float*)alloc((size_t)N_GRAPH * HID * 4);
    int* counts     = (int*)alloc((size_t)N_NODES * 4);
    int* row_ptr    = (int*)alloc((size_t)(N_NODES + 1) * 4);
    int* cursor     = (int*)alloc((size_t)N_NODES * 4);
    int* csr        = (int*)alloc((size_t)N_EDGES * 4);
    (void)ws_size; (void)in_sizes; (void)n_in; (void)out_size;

    // 1. init
    init_zero_kernel<<<(N_NODES + 255) / 256, 256, 0, stream>>>(counts, cursor, stats);

    // 2-4. fs, fd, skip GEMMs (128x128 tiles)
    dim3 gemm_grid((N_NODES + 127) / 128, F2 / 128);
    gemm128<false><<<gemm_grid, 256, 0, stream>>>(feat, W_src, b_src, FS, N_NODES, F2, nullptr, nullptr);
    gemm128<false><<<gemm_grid, 256, 0, stream>>>(feat, W_dst, b_dst, FD, N_NODES, F2, nullptr, nullptr);
    gemm128<false><<<gemm_grid, 256, 0, stream>>>(feat, W_skip, b_skip, h1, N_NODES, F2, nullptr, nullptr);

    // 5-7. CSR by dst
    hist_kernel<<<(N_EDGES + 255) / 256, 256, 0, stream>>>(dst, counts);
    scan_kernel<<<1, 1024, 0, stream>>>(counts, row_ptr);
    scatter_kernel<<<(N_EDGES + 255) / 256, 256, 0, stream>>>(dst, row_ptr, cursor, csr);

    // 8. edge scores (softmax numerator; shift-invariance => no max pass needed)
    edge_score_kernel<<<N_EDGES / 4, 256, 0, stream>>>(FS, FD, src, dst, attn, sexp);

    // 9. per-dst aggregation + ELU + skip
    aggregate_kernel<<<N_NODES, 256, 0, stream>>>(FS, sexp, csr, row_ptr, src, h1);

    // 10-11. BatchNorm stats -> fold into scale/shift
    bn_stats_kernel<<<250, 256, 0, stream>>>(h1, stats, 80);
    bn_finalize_kernel<<<1, 512, 0, stream>>>(stats, gamma, beta, bn_scale, bn_shift);

    // 12. hr = BN(h1) @ W_red + b_red  (BN folded into A-load)
    dim3 red_grid((N_NODES + 127) / 128, HID / 128);
    gemm128<true><<<red_grid, 256, 0, stream>>>(h1, W_red, b_red, hr, N_NODES, HID, bn_scale, bn_shift);

    // 13. gate
    gate_kernel<<<N_NODES / 4, 256, 0, stream>>>(hr, w_gate, b_gate, gate);

    // 14. per-graph pooling
    pool_kernel<<<N_GRAPH, 256, 0, stream>>>(hr, gate, gids, h_g);

    // 15. classifier
    classifier_kernel<<<N_GRAPH, 128, 0, stream>>>(h_g, W1, b1, W2, b2, out);
}

// Round 3
// 929.025 us; speedup vs baseline: 1.3740x; 1.1326x over previous
//
#include <hip/hip_runtime.h>
#include <math.h>

#define N_NODES 20000
#define N_EDGES 320000
#define N_GRAPH 64
#define IN_DIM  512
#define HID     256
#define F2      512   // HEADS*HID
#define EPS_BN  1e-5f
#define SLOPE   0.2f

typedef unsigned short u16;

// bf16 helpers: storage = upper 16 bits of fp32, round-to-nearest-even
__device__ __forceinline__ unsigned int pack_bf2(float a, float b) {
    unsigned int ua = __float_as_uint(a), ub = __float_as_uint(b);
    ua = (ua + 0x7fffu + ((ua >> 16) & 1u)) >> 16;
    ub = (ub + 0x7fffu + ((ub >> 16) & 1u)) & 0xffff0000u;
    return ua | ub;
}
__device__ __forceinline__ void unpack2(unsigned int u, float& lo, float& hi) {
    lo = __uint_as_float(u << 16);
    hi = __uint_as_float(u & 0xffff0000u);
}
__device__ __forceinline__ float lr(float x) { return fmaxf(x, SLOPE * x); }

// ---------------- init: zero the ws regions that need it ----------------
__global__ void init_zero_kernel(int* counts, int* cursor, float* stats) {
    int i = blockIdx.x * blockDim.x + threadIdx.x;
    if (i < N_NODES) { counts[i] = 0; cursor[i] = 0; }
    if (i < 1024) stats[i] = 0.f;
}

// ---------------- tiled fp32 GEMM: C[N,M] = X[N,512] @ W[512,M] + bias --
// 128x128 tile, BK=16, 8x8 microtile. OUT_BF16: round-store output as bf16.
// USE_BN: apply per-k scale/shift to X at load (folds BatchNorm into GEMM).
template <bool USE_BN, bool OUT_BF16>
__global__ __launch_bounds__(256) void gemm128(
    const float* __restrict__ X, const float* __restrict__ W,
    const float* __restrict__ bias, void* __restrict__ Cv,
    int Nrows, int M,
    const float* __restrict__ bscale, const float* __restrict__ bshift) {
    __shared__ float As[16][132];
    __shared__ float Bs[16][132];
    int tid = threadIdx.x;
    int row0 = blockIdx.x * 128;
    int col0 = blockIdx.y * 128;
    int tx = tid & 15, ty = tid >> 4;

    int f1 = tid + 256;
    int am0 = tid >> 2, ak0 = (tid & 3) << 2;
    int am1 = f1 >> 2;
    int bk0 = tid >> 5, bn0 = (tid & 31) << 2;
    int bk1 = f1 >> 5;

    float acc[8][8];
#pragma unroll
    for (int i = 0; i < 8; i++)
#pragma unroll
        for (int j = 0; j < 8; j++) acc[i][j] = 0.f;

    for (int k0 = 0; k0 < 512; k0 += 16) {
        float4 av0 = make_float4(0.f, 0.f, 0.f, 0.f);
        float4 av1 = make_float4(0.f, 0.f, 0.f, 0.f);
        int gr0 = row0 + am0, gr1 = row0 + am1;
        if (gr0 < Nrows) av0 = *(const float4*)(X + (size_t)gr0 * 512 + k0 + ak0);
        if (gr1 < Nrows) av1 = *(const float4*)(X + (size_t)gr1 * 512 + k0 + ak0);
        if (USE_BN) {
            float s0 = bscale[k0 + ak0 + 0], h0 = bshift[k0 + ak0 + 0];
            float s1 = bscale[k0 + ak0 + 1], h1 = bshift[k0 + ak0 + 1];
            float s2 = bscale[k0 + ak0 + 2], h2 = bshift[k0 + ak0 + 2];
            float s3 = bscale[k0 + ak0 + 3], h3 = bshift[k0 + ak0 + 3];
            av0.x = av0.x * s0 + h0; av0.y = av0.y * s1 + h1;
            av0.z = av0.z * s2 + h2; av0.w = av0.w * s3 + h3;
            av1.x = av1.x * s0 + h0; av1.y = av1.y * s1 + h1;
            av1.z = av1.z * s2 + h2; av1.w = av1.w * s3 + h3;
        }
        float4 bv0 = *(const float4*)(W + (size_t)(k0 + bk0) * M + col0 + bn0);
        float4 bv1 = *(const float4*)(W + (size_t)(k0 + bk1) * M + col0 + bn0);

        __syncthreads();
        As[ak0 + 0][am0] = av0.x; As[ak0 + 1][am0] = av0.y;
        As[ak0 + 2][am0] = av0.z; As[ak0 + 3][am0] = av0.w;
        As[ak0 + 0][am1] = av1.x; As[ak0 + 1][am1] = av1.y;
        As[ak0 + 2][am1] = av1.z; As[ak0 + 3][am1] = av1.w;
        *(float4*)&Bs[bk0][bn0] = bv0;
        *(float4*)&Bs[bk1][bn0] = bv1;
        __syncthreads();

#pragma unroll
        for (int kk = 0; kk < 16; kk++) {
            float a[8], b[8];
            *(float4*)&a[0] = *(const float4*)&As[kk][ty * 4];
            *(float4*)&a[4] = *(const float4*)&As[kk][64 + ty * 4];
            *(float4*)&b[0] = *(const float4*)&Bs[kk][tx * 4];
            *(float4*)&b[4] = *(const float4*)&Bs[kk][64 + tx * 4];
#pragma unroll
            for (int i = 0; i < 8; i++)
#pragma unroll
                for (int j = 0; j < 8; j++) acc[i][j] += a[i] * b[j];
        }
    }

    float blo[4], bhi[4];
#pragma unroll
    for (int j = 0; j < 4; j++) {
        blo[j] = bias[col0 + tx * 4 + j];
        bhi[j] = bias[col0 + 64 + tx * 4 + j];
    }
#pragma unroll
    for (int ih = 0; ih < 2; ih++) {
#pragma unroll
        for (int i = 0; i < 4; i++) {
            int r = row0 + ih * 64 + ty * 4 + i;
            if (r < Nrows) {
                int ai = ih * 4 + i;
                if (OUT_BF16) {
                    u16* C16 = (u16*)Cv;
                    uint2 w;
                    w.x = pack_bf2(acc[ai][0] + blo[0], acc[ai][1] + blo[1]);
                    w.y = pack_bf2(acc[ai][2] + blo[2], acc[ai][3] + blo[3]);
                    *(uint2*)(C16 + (size_t)r * M + col0 + tx * 4) = w;
                    w.x = pack_bf2(acc[ai][4] + bhi[0], acc[ai][5] + bhi[1]);
                    w.y = pack_bf2(acc[ai][6] + bhi[2], acc[ai][7] + bhi[3]);
                    *(uint2*)(C16 + (size_t)r * M + col0 + 64 + tx * 4) = w;
                } else {
                    float* C = (float*)Cv;
                    float4 v;
                    v.x = acc[ai][0] + blo[0]; v.y = acc[ai][1] + blo[1];
                    v.z = acc[ai][2] + blo[2]; v.w = acc[ai][3] + blo[3];
                    *(float4*)(C + (size_t)r * M + col0 + tx * 4) = v;
                    v.x = acc[ai][4] + bhi[0]; v.y = acc[ai][5] + bhi[1];
                    v.z = acc[ai][6] + bhi[2]; v.w = acc[ai][7] + bhi[3];
                    *(float4*)(C + (size_t)r * M + col0 + 64 + tx * 4) = v;
                }
            }
        }
    }
}

// ---------------- CSR build ----------------
__global__ void hist_kernel(const int* __restrict__ dst, int* __restrict__ counts) {
    int e = blockIdx.x * blockDim.x + threadIdx.x;
    if (e < N_EDGES) atomicAdd(&counts[dst[e]], 1);
}

__global__ __launch_bounds__(1024) void scan_kernel(const int* __restrict__ counts,
                                                    int* __restrict__ row_ptr) {
    __shared__ int buf[1024];
    __shared__ int carry;
    int tid = threadIdx.x;
    if (tid == 0) { carry = 0; row_ptr[0] = 0; }
    __syncthreads();
    for (int base = 0; base < N_NODES; base += 1024) {
        int v = (base + tid < N_NODES) ? counts[base + tid] : 0;
        buf[tid] = v;
        __syncthreads();
        for (int off = 1; off < 1024; off <<= 1) {
            int t = (tid >= off) ? buf[tid - off] : 0;
            __syncthreads();
            buf[tid] += t;
            __syncthreads();
        }
        if (base + tid < N_NODES) row_ptr[base + tid + 1] = carry + buf[tid];
        __syncthreads();
        if (tid == 0) carry += buf[1023];
        __syncthreads();
    }
}

// writes csr_src[i] = src of the edge occupying CSR slot i (grouped by dst)
__global__ void scatter_kernel(const int* __restrict__ src, const int* __restrict__ dst,
                               const int* __restrict__ row_ptr,
                               int* __restrict__ cursor, int* __restrict__ csr_src) {
    int e = blockIdx.x * blockDim.x + threadIdx.x;
    if (e < N_EDGES) {
        int d = dst[e];
        int pos = atomicAdd(&cursor[d], 1);
        csr_src[row_ptr[d] + pos] = src[e];
    }
}

// -------- fused edge phase: scores + softmax + aggregation + ELU + skip --
// one block per dst node; FS/FD in bf16 (1 KB rows). Pass A: per-edge score
// (4 waves, lane covers dims 8l..8l+8, halves of the wave = the two heads),
// exp stored to sexp[slot] + denom in LDS. Pass B: weighted sum, thread owns
// dims 2*tid, 2*tid+1; alphas/srcs staged in LDS in 256-edge chunks.
__global__ __launch_bounds__(256) void edge_fused_kernel(
    const u16* __restrict__ FS16, const u16* __restrict__ FD16,
    const float* __restrict__ attn, const int* __restrict__ csr_src,
    const int* __restrict__ row_ptr, float* __restrict__ sexp,
    float* __restrict__ h1) {
    int n = blockIdx.x;
    int tid = threadIdx.x;
    int lane = tid & 63, wave = tid >> 6;
    int beg = row_ptr[n], end = row_ptr[n + 1];
    __shared__ float al0[256], al1[256];
    __shared__ int src_s[256];
    __shared__ float den[2];
    if (tid < 2) den[tid] = 0.f;

    float fdv[8], aw[8];
    {
        uint4 q = *(const uint4*)(FD16 + (size_t)n * 512 + 8 * lane);
        unpack2(q.x, fdv[0], fdv[1]); unpack2(q.y, fdv[2], fdv[3]);
        unpack2(q.z, fdv[4], fdv[5]); unpack2(q.w, fdv[6], fdv[7]);
        float4 a0 = *(const float4*)(attn + 8 * lane);
        float4 a1 = *(const float4*)(attn + 8 * lane + 4);
        aw[0] = a0.x; aw[1] = a0.y; aw[2] = a0.z; aw[3] = a0.w;
        aw[4] = a1.x; aw[5] = a1.y; aw[6] = a1.z; aw[7] = a1.w;
    }
    __syncthreads();

    // ---- pass A: scores ----
    float dpriv = 0.f;
    for (int i = beg + wave; i < end; i += 4) {
        int s = csr_src[i];
        uint4 q = *(const uint4*)(FS16 + (size_t)s * 512 + 8 * lane);
        float f0, f1, p = 0.f;
        unpack2(q.x, f0, f1); p += lr(f0 + fdv[0]) * aw[0] + lr(f1 + fdv[1]) * aw[1];
        unpack2(q.y, f0, f1); p += lr(f0 + fdv[2]) * aw[2] + lr(f1 + fdv[3]) * aw[3];
        unpack2(q.z, f0, f1); p += lr(f0 + fdv[4]) * aw[4] + lr(f1 + fdv[5]) * aw[5];
        unpack2(q.w, f0, f1); p += lr(f0 + fdv[6]) * aw[6] + lr(f1 + fdv[7]) * aw[7];
#pragma unroll
        for (int off = 16; off > 0; off >>= 1) p += __shfl_down(p, off, 32);
        if ((lane & 31) == 0) {  // lane 0 = head0, lane 32 = head1
            float ex = expf(p);   // shift-invariant: no max pass needed, |p| ~ O(1)
            sexp[2 * i + (lane >> 5)] = ex;
            dpriv += ex;
        }
    }
    if (lane == 0) atomicAdd(&den[0], dpriv);
    if (lane == 32) atomicAdd(&den[1], dpriv);
    __syncthreads();
    float inv0 = den[0] > 0.f ? 1.f / den[0] : 0.f;
    float inv1 = den[1] > 0.f ? 1.f / den[1] : 0.f;

    // ---- pass B: weighted aggregation ----
    float acc_a = 0.f, acc_b = 0.f;
    bool h0 = tid < 128;  // dims 2*tid, 2*tid+1 belong to head0 iff tid<128
    for (int cbeg = beg; cbeg < end; cbeg += 256) {
        int cnt = min(256, end - cbeg);
        if (tid < cnt) {
            int i = cbeg + tid;
            src_s[tid] = csr_src[i];
            al0[tid] = sexp[2 * i] * inv0;
            al1[tid] = sexp[2 * i + 1] * inv1;
        }
        __syncthreads();
        for (int j = 0; j < cnt; j++) {
            float al = h0 ? al0[j] : al1[j];
            unsigned int u = *(const unsigned int*)(FS16 + (size_t)src_s[j] * 512 + 2 * tid);
            float f0, f1; unpack2(u, f0, f1);
            acc_a += al * f0; acc_b += al * f1;
        }
        __syncthreads();
    }
    // ELU + skip (skip GEMM already wrote into h1)
    float e0 = acc_a > 0.f ? acc_a : expm1f(acc_a);
    float e1 = acc_b > 0.f ? acc_b : expm1f(acc_b);
    size_t base = (size_t)n * 512 + 2 * tid;
    float2 sk = *(float2*)(h1 + base);
    sk.x += e0; sk.y += e1;
    *(float2*)(h1 + base) = sk;
}

// ---------------- BatchNorm stats ----------------
__global__ __launch_bounds__(256) void bn_stats_kernel(const float* __restrict__ h1,
                                                       float* __restrict__ stats,
                                                       int rows_per_block) {
    int tid = threadIdx.x;
    int r0 = blockIdx.x * rows_per_block;
    int r1 = min(r0 + rows_per_block, N_NODES);
    float s0 = 0.f, q0 = 0.f, s1 = 0.f, q1 = 0.f;
    for (int r = r0; r < r1; r++) {
        float a = h1[(size_t)r * F2 + tid];
        float b = h1[(size_t)r * F2 + 256 + tid];
        s0 += a; q0 += a * a;
        s1 += b; q1 += b * b;
    }
    atomicAdd(&stats[tid], s0);
    atomicAdd(&stats[256 + tid], s1);
    atomicAdd(&stats[512 + tid], q0);
    atomicAdd(&stats[512 + 256 + tid], q1);
}

__global__ void bn_finalize_kernel(const float* __restrict__ stats,
                                   const float* __restrict__ gamma,
                                   const float* __restrict__ beta,
                                   float* __restrict__ bscale, float* __restrict__ bshift) {
    int c = threadIdx.x;  // 512 threads
    float mu = stats[c] / (float)N_NODES;
    float var = stats[512 + c] / (float)N_NODES - mu * mu;
    float sc = gamma[c] * rsqrtf(var + EPS_BN);
    bscale[c] = sc;
    bshift[c] = beta[c] - mu * sc;
}

// ---------------- gate scores ----------------
__global__ __launch_bounds__(256) void gate_kernel(const float* __restrict__ hr,
                                                   const float* __restrict__ wg,
                                                   const float* __restrict__ bg,
                                                   float* __restrict__ gate) {
    int n = blockIdx.x * 4 + (threadIdx.x >> 6);
    int lane = threadIdx.x & 63;
    const float4* row = (const float4*)(hr + (size_t)n * HID);
    const float4* w = (const float4*)wg;
    float4 a = row[lane], b = w[lane];
    float p = a.x * b.x + a.y * b.y + a.z * b.z + a.w * b.w;
#pragma unroll
    for (int off = 32; off > 0; off >>= 1) p += __shfl_down(p, off, 64);
    if (lane == 0) gate[n] = p + bg[0];
}

// ---------------- per-graph attention pooling ----------------
__device__ __forceinline__ int lower_bound_dev(const int* a, int n, int v) {
    int lo = 0, hi = n;
    while (lo < hi) {
        int mid = (lo + hi) >> 1;
        if (a[mid] < v) lo = mid + 1; else hi = mid;
    }
    return lo;
}

__global__ __launch_bounds__(256) void pool_kernel(const float* __restrict__ hr,
                                                   const float* __restrict__ gate,
                                                   const int* __restrict__ gids,
                                                   float* __restrict__ h_g) {
    int g = blockIdx.x;
    int tid = threadIdx.x;
    int start = lower_bound_dev(gids, N_NODES, g);
    int end = lower_bound_dev(gids, N_NODES, g + 1);
    __shared__ float red[256];
    __shared__ float wa[256];
    if (start >= end) { h_g[g * HID + tid] = 0.f; return; }
    float m = -3.4e38f;
    for (int i = start + tid; i < end; i += 256) m = fmaxf(m, gate[i]);
    red[tid] = m; __syncthreads();
    for (int off = 128; off > 0; off >>= 1) { if (tid < off) red[tid] = fmaxf(red[tid], red[tid + off]); __syncthreads(); }
    float gmax = red[0];
    __syncthreads();
    float se = 0.f;
    for (int i = start + tid; i < end; i += 256) se += expf(gate[i] - gmax);
    red[tid] = se; __syncthreads();
    for (int off = 128; off > 0; off >>= 1) { if (tid < off) red[tid] += red[tid + off]; __syncthreads(); }
    float ssum = red[0];
    __syncthreads();
    float acc = 0.f;
    for (int cbeg = start; cbeg < end; cbeg += 256) {
        int cnt = min(256, end - cbeg);
        if (tid < cnt) wa[tid] = expf(gate[cbeg + tid] - gmax);
        __syncthreads();
        for (int i = 0; i < cnt; i++) acc += wa[i] * hr[(size_t)(cbeg + i) * HID + tid];
        __syncthreads();
    }
    h_g[g * HID + tid] = acc / ssum;
}

// ---------------- classifier ----------------
__global__ __launch_bounds__(128) void classifier_kernel(
    const float* __restrict__ h_g, const float* __restrict__ W1, const float* __restrict__ b1,
    const float* __restrict__ W2, const float* __restrict__ b2, float* __restrict__ out) {
    int g = blockIdx.x;
    int tid = threadIdx.x;  // 128
    __shared__ float hg[256];
    __shared__ float z1[128];
    hg[tid] = h_g[g * HID + tid];
    hg[tid + 128] = h_g[g * HID + tid + 128];
    __syncthreads();
    float a = b1[tid];
#pragma unroll 8
    for (int k = 0; k < 256; k++) a += hg[k] * W1[k * 128 + tid];
    z1[tid] = a > 0.f ? a : 0.f;
    __syncthreads();
    if (tid < 10) {
        float o = b2[tid];
#pragma unroll 8
        for (int j = 0; j < 128; j++) o += z1[j] * W2[j * 10 + tid];
        out[g * 10 + tid] = o;
    }
}

// ---------------- launcher ----------------
extern "C" void kernel_launch(void* const* d_in, const int* in_sizes, int n_in,
                              void* d_out, int out_size, void* d_ws, size_t ws_size,
                              hipStream_t stream) {
    const float* feat   = (const float*)d_in[0];
    const int*   src    = (const int*)d_in[1];
    const int*   dst    = (const int*)d_in[2];
    const int*   gids   = (const int*)d_in[3];
    const float* W_src  = (const float*)d_in[4];
    const float* b_src  = (const float*)d_in[5];
    const float* W_dst  = (const float*)d_in[6];
    const float* b_dst  = (const float*)d_in[7];
    const float* attn   = (const float*)d_in[8];
    const float* W_skip = (const float*)d_in[9];
    const float* b_skip = (const float*)d_in[10];
    const float* gamma  = (const float*)d_in[11];
    const float* beta   = (const float*)d_in[12];
    const float* W_red  = (const float*)d_in[13];
    const float* b_red  = (const float*)d_in[14];
    const float* w_gate = (const float*)d_in[15];
    const float* b_gate = (const float*)d_in[16];
    const float* W1     = (const float*)d_in[17];
    const float* b1     = (const float*)d_in[18];
    const float* W2     = (const float*)d_in[19];
    const float* b2     = (const float*)d_in[20];
    float* out = (float*)d_out;

    char* p = (char*)d_ws;
    auto alloc = [&](size_t bytes) -> char* {
        char* r = p;
        p += (bytes + 255) & ~(size_t)255;
        return r;
    };
    u16*   FS16     = (u16*)alloc((size_t)N_NODES * F2 * 2);
    u16*   FD16     = (u16*)alloc((size_t)N_NODES * F2 * 2);
    float* h1       = (float*)alloc((size_t)N_NODES * F2 * 4);   // skip lands here, then elu(gat)+skip
    float* hr       = (float*)alloc((size_t)N_NODES * HID * 4);
    float* sexp     = (float*)alloc((size_t)N_EDGES * 2 * 4);
    float* gate     = (float*)alloc((size_t)N_NODES * 4);
    float* stats    = (float*)alloc(1024 * 4);
    float* bn_scale = (float*)alloc(512 * 4);
    float* bn_shift = (float*)alloc(512 * 4);
    float* h_g      = (float*)alloc((size_t)N_GRAPH * HID * 4);
    int* counts     = (int*)alloc((size_t)N_NODES * 4);
    int* row_ptr    = (int*)alloc((size_t)(N_NODES + 1) * 4);
    int* cursor     = (int*)alloc((size_t)N_NODES * 4);
    int* csr_src    = (int*)alloc((size_t)N_EDGES * 4);
    (void)ws_size; (void)in_sizes; (void)n_in; (void)out_size;

    // 1. init
    init_zero_kernel<<<(N_NODES + 255) / 256, 256, 0, stream>>>(counts, cursor, stats);

    // 2-4. fs, fd (bf16 out), skip (fp32 out) GEMMs
    dim3 gemm_grid((N_NODES + 127) / 128, F2 / 128);
    gemm128<false, true ><<<gemm_grid, 256, 0, stream>>>(feat, W_src, b_src, FS16, N_NODES, F2, nullptr, nullptr);
    gemm128<false, true ><<<gemm_grid, 256, 0, stream>>>(feat, W_dst, b_dst, FD16, N_NODES, F2, nullptr, nullptr);
    gemm128<false, false><<<gemm_grid, 256, 0, stream>>>(feat, W_skip, b_skip, h1, N_NODES, F2, nullptr, nullptr);

    // 5-7. CSR by dst (csr_src holds src indices per slot)
    hist_kernel<<<(N_EDGES + 255) / 256, 256, 0, stream>>>(dst, counts);
    scan_kernel<<<1, 1024, 0, stream>>>(counts, row_ptr);
    scatter_kernel<<<(N_EDGES + 255) / 256, 256, 0, stream>>>(src, dst, row_ptr, cursor, csr_src);

    // 8. fused edge phase: scores + softmax + aggregation + ELU + skip
    edge_fused_kernel<<<N_NODES, 256, 0, stream>>>(FS16, FD16, attn, csr_src, row_ptr, sexp, h1);

    // 9-10. BatchNorm stats -> fold into scale/shift
    bn_stats_kernel<<<250, 256, 0, stream>>>(h1, stats, 80);
    bn_finalize_kernel<<<1, 512, 0, stream>>>(stats, gamma, beta, bn_scale, bn_shift);

    // 11. hr = BN(h1) @ W_red + b_red  (BN folded into A-load)
    dim3 red_grid((N_NODES + 127) / 128, HID / 128);
    gemm128<true, false><<<red_grid, 256, 0, stream>>>(h1, W_red, b_red, hr, N_NODES, HID, bn_scale, bn_shift);

    // 12. gate
    gate_kernel<<<N_NODES / 4, 256, 0, stream>>>(hr, w_gate, b_gate, gate);

    // 13. per-graph pooling
    pool_kernel<<<N_GRAPH, 256, 0, stream>>>(hr, gate, gids, h_g);

    // 14. classifier
    classifier_kernel<<<N_GRAPH, 128, 0, stream>>>(h_g, W1, b1, W2, b2, out);
}

// Round 4
// 679.013 us; speedup vs baseline: 1.8799x; 1.3682x over previous
//
#include <hip/hip_runtime.h>
#include <math.h>

#define N_NODES 20000
#define N_EDGES 320000
#define N_GRAPH 64
#define IN_DIM  512
#define HID     256
#define F2      512   // HEADS*HID
#define EPS_BN  1e-5f
#define SLOPE   0.2f

typedef unsigned short u16;
typedef __attribute__((ext_vector_type(8))) short bf16x8;
typedef __attribute__((ext_vector_type(4))) float floatx4;

// bf16 helpers: storage = upper 16 bits of fp32, round-to-nearest-even
__device__ __forceinline__ u16 bf_hi(float x) {
    unsigned int u = __float_as_uint(x);
    return (u16)((u + 0x7fffu + ((u >> 16) & 1u)) >> 16);
}
__device__ __forceinline__ float bf_val(u16 h) {
    return __uint_as_float((unsigned int)h << 16);
}
__device__ __forceinline__ unsigned int pack_bf2(float a, float b) {
    unsigned int ua = __float_as_uint(a), ub = __float_as_uint(b);
    ua = (ua + 0x7fffu + ((ua >> 16) & 1u)) >> 16;
    ub = (ub + 0x7fffu + ((ub >> 16) & 1u)) & 0xffff0000u;
    return ua | ub;
}
__device__ __forceinline__ void unpack2(unsigned int u, float& lo, float& hi) {
    lo = __uint_as_float(u << 16);
    hi = __uint_as_float(u & 0xffff0000u);
}
__device__ __forceinline__ float lr(float x) { return fmaxf(x, SLOPE * x); }

// ---------------- init: zero the ws regions that need it ----------------
__global__ void init_zero_kernel(int* counts, int* cursor, float* stats) {
    int i = blockIdx.x * blockDim.x + threadIdx.x;
    if (i < N_NODES) { counts[i] = 0; cursor[i] = 0; }
    if (i < 1024) stats[i] = 0.f;
}

// ---------------- split feat into bf16 hi/lo (row-major preserved) ------
__global__ __launch_bounds__(256) void split_feat_kernel(
    const float* __restrict__ X, u16* __restrict__ Hi, u16* __restrict__ Lo,
    int total8) {
    int i = blockIdx.x * 256 + threadIdx.x;
    if (i >= total8) return;
    size_t base = (size_t)i * 8;
    float4 x0 = *(const float4*)(X + base);
    float4 x1 = *(const float4*)(X + base + 4);
    float xs[8] = {x0.x, x0.y, x0.z, x0.w, x1.x, x1.y, x1.z, x1.w};
    union { u16 s[8]; uint4 v; } h, l;
#pragma unroll
    for (int j = 0; j < 8; j++) {
        u16 hh = bf_hi(xs[j]);
        h.s[j] = hh;
        l.s[j] = bf_hi(xs[j] - bf_val(hh));
    }
    *(uint4*)(Hi + base) = h.v;
    *(uint4*)(Lo + base) = l.v;
}

// --------- transpose + split the 3 weights: W[k][n] -> Wt[w][n][k] hi/lo -
__global__ __launch_bounds__(256) void split_wt_kernel(
    const float* __restrict__ Ws, const float* __restrict__ Wd,
    const float* __restrict__ Wk, u16* __restrict__ Hi, u16* __restrict__ Lo) {
    __shared__ float t[32][33];
    int w = blockIdx.z;
    const float* W = (w == 0) ? Ws : ((w == 1) ? Wd : Wk);
    int k0 = blockIdx.x * 32, n0 = blockIdx.y * 32;
    int tx = threadIdx.x, ty = threadIdx.y;  // 32 x 8
#pragma unroll
    for (int i = 0; i < 4; i++)
        t[ty * 4 + i][tx] = W[(size_t)(k0 + ty * 4 + i) * 512 + n0 + tx];
    __syncthreads();
#pragma unroll
    for (int i = 0; i < 4; i++) {
        float x = t[tx][ty * 4 + i];  // = W[k0+tx][n0+ty*4+i]
        u16 hh = bf_hi(x);
        size_t o = ((size_t)w * 512 + n0 + ty * 4 + i) * 512 + k0 + tx;
        Hi[o] = hh;
        Lo[o] = bf_hi(x - bf_val(hh));
    }
}

// ------- fused 3-way MFMA GEMM: {fs,fd,skip} = feat @ {W_src,W_dst,W_skip} ---
// split-bf16 (hi+lo), 3 MFMA terms per tile -> fp32-class accuracy.
// 128x128 C-tile/block, 4 waves each 64x64 (4x4 of 16x16x32 MFMA tiles).
// A staged in LDS (stride 40 elems: b128-minimal banking); B-frags read
// directly from pre-transposed Wt[n][k] (L2-resident, 3 MB).
__global__ __launch_bounds__(256) void gemm_mfma_fused(
    const u16* __restrict__ Fhi, const u16* __restrict__ Flo,
    const u16* __restrict__ Whi, const u16* __restrict__ Wlo,
    const float* __restrict__ b_src, const float* __restrict__ b_dst,
    const float* __restrict__ b_skip,
    u16* __restrict__ FS16, u16* __restrict__ FD16, float* __restrict__ h1) {
    __shared__ u16 AsHi[128 * 40];
    __shared__ u16 AsLo[128 * 40];
    int tid = threadIdx.x;
    int w_idx = blockIdx.y >> 2;
    int col0 = (blockIdx.y & 3) * 128;
    int row0 = blockIdx.x * 128;
    int lane = tid & 63, wave = tid >> 6;
    int wm = (wave & 1) * 64, wn = (wave >> 1) * 64;
    int quad = lane >> 4, l16 = lane & 15;

    // staging map: thread t -> row t>>1, 16-elem half (t&1)
    int sr = tid >> 1;
    int sh = (tid & 1) * 16;
    int grow = row0 + sr;
    bool arow_ok = grow < N_NODES;
    const u16* gA_hi = Fhi + (size_t)grow * 512 + sh;
    const u16* gA_lo = Flo + (size_t)grow * 512 + sh;
    u16* sA_hi = &AsHi[sr * 40 + sh];
    u16* sA_lo = &AsLo[sr * 40 + sh];

    const u16* Wb_hi = Whi + (size_t)w_idx * 512 * 512;
    const u16* Wb_lo = Wlo + (size_t)w_idx * 512 * 512;

    floatx4 acc[4][4];
#pragma unroll
    for (int i = 0; i < 4; i++)
#pragma unroll
        for (int j = 0; j < 4; j++) acc[i][j] = (floatx4){0.f, 0.f, 0.f, 0.f};

    for (int k0 = 0; k0 < 512; k0 += 32) {
        uint4 a0 = make_uint4(0, 0, 0, 0), a1 = a0, q0 = a0, q1 = a0;
        if (arow_ok) {
            a0 = *(const uint4*)(gA_hi + k0);
            a1 = *(const uint4*)(gA_hi + k0 + 8);
            q0 = *(const uint4*)(gA_lo + k0);
            q1 = *(const uint4*)(gA_lo + k0 + 8);
        }
        union { uint4 u; bf16x8 v; } bh[4], bl[4];
#pragma unroll
        for (int nt = 0; nt < 4; nt++) {
            size_t off = (size_t)(col0 + wn + nt * 16 + l16) * 512 + k0 + quad * 8;
            bh[nt].u = *(const uint4*)(Wb_hi + off);
            bl[nt].u = *(const uint4*)(Wb_lo + off);
        }
        __syncthreads();  // previous iteration's LDS reads complete
        *(uint4*)(sA_hi + 0) = a0;
        *(uint4*)(sA_hi + 8) = a1;
        *(uint4*)(sA_lo + 0) = q0;
        *(uint4*)(sA_lo + 8) = q1;
        __syncthreads();
#pragma unroll
        for (int mt = 0; mt < 4; mt++) {
            int me = (wm + mt * 16 + l16) * 40 + quad * 8;
            bf16x8 ah = *(const bf16x8*)&AsHi[me];
            bf16x8 al = *(const bf16x8*)&AsLo[me];
#pragma unroll
            for (int nt = 0; nt < 4; nt++) {
                acc[mt][nt] = __builtin_amdgcn_mfma_f32_16x16x32_bf16(ah, bh[nt].v, acc[mt][nt], 0, 0, 0);
                acc[mt][nt] = __builtin_amdgcn_mfma_f32_16x16x32_bf16(ah, bl[nt].v, acc[mt][nt], 0, 0, 0);
                acc[mt][nt] = __builtin_amdgcn_mfma_f32_16x16x32_bf16(al, bh[nt].v, acc[mt][nt], 0, 0, 0);
            }
        }
    }

    // epilogue: + bias, store (w 0/1 -> bf16, w 2 -> fp32 h1)
    const float* bias = (w_idx == 0) ? b_src : ((w_idx == 1) ? b_dst : b_skip);
    float bv[4];
#pragma unroll
    for (int nt = 0; nt < 4; nt++) bv[nt] = bias[col0 + wn + nt * 16 + l16];
#pragma unroll
    for (int mt = 0; mt < 4; mt++) {
#pragma unroll
        for (int r = 0; r < 4; r++) {
            int m = row0 + wm + mt * 16 + quad * 4 + r;
            if (m < N_NODES) {
#pragma unroll
                for (int nt = 0; nt < 4; nt++) {
                    int n = col0 + wn + nt * 16 + l16;
                    float v = acc[mt][nt][r] + bv[nt];
                    if (w_idx == 0)      FS16[(size_t)m * 512 + n] = bf_hi(v);
                    else if (w_idx == 1) FD16[(size_t)m * 512 + n] = bf_hi(v);
                    else                 h1[(size_t)m * 512 + n] = v;
                }
            }
        }
    }
}

// ---------------- tiled fp32 GEMM (reducer): BN folded into A-load ------
template <bool USE_BN>
__global__ __launch_bounds__(256) void gemm128(
    const float* __restrict__ X, const float* __restrict__ W,
    const float* __restrict__ bias, float* __restrict__ C,
    int Nrows, int M,
    const float* __restrict__ bscale, const float* __restrict__ bshift) {
    __shared__ float As[16][132];
    __shared__ float Bs[16][132];
    int tid = threadIdx.x;
    int row0 = blockIdx.x * 128;
    int col0 = blockIdx.y * 128;
    int tx = tid & 15, ty = tid >> 4;

    int f1 = tid + 256;
    int am0 = tid >> 2, ak0 = (tid & 3) << 2;
    int am1 = f1 >> 2;
    int bk0 = tid >> 5, bn0 = (tid & 31) << 2;
    int bk1 = f1 >> 5;

    float acc[8][8];
#pragma unroll
    for (int i = 0; i < 8; i++)
#pragma unroll
        for (int j = 0; j < 8; j++) acc[i][j] = 0.f;

    for (int k0 = 0; k0 < 512; k0 += 16) {
        float4 av0 = make_float4(0.f, 0.f, 0.f, 0.f);
        float4 av1 = make_float4(0.f, 0.f, 0.f, 0.f);
        int gr0 = row0 + am0, gr1 = row0 + am1;
        if (gr0 < Nrows) av0 = *(const float4*)(X + (size_t)gr0 * 512 + k0 + ak0);
        if (gr1 < Nrows) av1 = *(const float4*)(X + (size_t)gr1 * 512 + k0 + ak0);
        if (USE_BN) {
            float s0 = bscale[k0 + ak0 + 0], h0 = bshift[k0 + ak0 + 0];
            float s1 = bscale[k0 + ak0 + 1], h1 = bshift[k0 + ak0 + 1];
            float s2 = bscale[k0 + ak0 + 2], h2 = bshift[k0 + ak0 + 2];
            float s3 = bscale[k0 + ak0 + 3], h3 = bshift[k0 + ak0 + 3];
            av0.x = av0.x * s0 + h0; av0.y = av0.y * s1 + h1;
            av0.z = av0.z * s2 + h2; av0.w = av0.w * s3 + h3;
            av1.x = av1.x * s0 + h0; av1.y = av1.y * s1 + h1;
            av1.z = av1.z * s2 + h2; av1.w = av1.w * s3 + h3;
        }
        float4 bv0 = *(const float4*)(W + (size_t)(k0 + bk0) * M + col0 + bn0);
        float4 bv1 = *(const float4*)(W + (size_t)(k0 + bk1) * M + col0 + bn0);

        __syncthreads();
        As[ak0 + 0][am0] = av0.x; As[ak0 + 1][am0] = av0.y;
        As[ak0 + 2][am0] = av0.z; As[ak0 + 3][am0] = av0.w;
        As[ak0 + 0][am1] = av1.x; As[ak0 + 1][am1] = av1.y;
        As[ak0 + 2][am1] = av1.z; As[ak0 + 3][am1] = av1.w;
        *(float4*)&Bs[bk0][bn0] = bv0;
        *(float4*)&Bs[bk1][bn0] = bv1;
        __syncthreads();

#pragma unroll
        for (int kk = 0; kk < 16; kk++) {
            float a[8], b[8];
            *(float4*)&a[0] = *(const float4*)&As[kk][ty * 4];
            *(float4*)&a[4] = *(const float4*)&As[kk][64 + ty * 4];
            *(float4*)&b[0] = *(const float4*)&Bs[kk][tx * 4];
            *(float4*)&b[4] = *(const float4*)&Bs[kk][64 + tx * 4];
#pragma unroll
            for (int i = 0; i < 8; i++)
#pragma unroll
                for (int j = 0; j < 8; j++) acc[i][j] += a[i] * b[j];
        }
    }

    float blo[4], bhi_[4];
#pragma unroll
    for (int j = 0; j < 4; j++) {
        blo[j] = bias[col0 + tx * 4 + j];
        bhi_[j] = bias[col0 + 64 + tx * 4 + j];
    }
#pragma unroll
    for (int ih = 0; ih < 2; ih++) {
#pragma unroll
        for (int i = 0; i < 4; i++) {
            int r = row0 + ih * 64 + ty * 4 + i;
            if (r < Nrows) {
                int ai = ih * 4 + i;
                float4 v;
                v.x = acc[ai][0] + blo[0]; v.y = acc[ai][1] + blo[1];
                v.z = acc[ai][2] + blo[2]; v.w = acc[ai][3] + blo[3];
                *(float4*)(C + (size_t)r * M + col0 + tx * 4) = v;
                v.x = acc[ai][4] + bhi_[0]; v.y = acc[ai][5] + bhi_[1];
                v.z = acc[ai][6] + bhi_[2]; v.w = acc[ai][7] + bhi_[3];
                *(float4*)(C + (size_t)r * M + col0 + 64 + tx * 4) = v;
            }
        }
    }
}

// ---------------- CSR build ----------------
__global__ void hist_kernel(const int* __restrict__ dst, int* __restrict__ counts) {
    int e = blockIdx.x * blockDim.x + threadIdx.x;
    if (e < N_EDGES) atomicAdd(&counts[dst[e]], 1);
}

__global__ __launch_bounds__(1024) void scan_kernel(const int* __restrict__ counts,
                                                    int* __restrict__ row_ptr) {
    __shared__ int buf[1024];
    __shared__ int carry;
    int tid = threadIdx.x;
    if (tid == 0) { carry = 0; row_ptr[0] = 0; }
    __syncthreads();
    for (int base = 0; base < N_NODES; base += 1024) {
        int v = (base + tid < N_NODES) ? counts[base + tid] : 0;
        buf[tid] = v;
        __syncthreads();
        for (int off = 1; off < 1024; off <<= 1) {
            int t = (tid >= off) ? buf[tid - off] : 0;
            __syncthreads();
            buf[tid] += t;
            __syncthreads();
        }
        if (base + tid < N_NODES) row_ptr[base + tid + 1] = carry + buf[tid];
        __syncthreads();
        if (tid == 0) carry += buf[1023];
        __syncthreads();
    }
}

__global__ void scatter_kernel(const int* __restrict__ src, const int* __restrict__ dst,
                               const int* __restrict__ row_ptr,
                               int* __restrict__ cursor, int* __restrict__ csr_src) {
    int e = blockIdx.x * blockDim.x + threadIdx.x;
    if (e < N_EDGES) {
        int d = dst[e];
        int pos = atomicAdd(&cursor[d], 1);
        csr_src[row_ptr[d] + pos] = src[e];
    }
}

// -------- fused edge phase: scores + softmax + aggregation + ELU + skip --
__global__ __launch_bounds__(256) void edge_fused_kernel(
    const u16* __restrict__ FS16, const u16* __restrict__ FD16,
    const float* __restrict__ attn, const int* __restrict__ csr_src,
    const int* __restrict__ row_ptr, float* __restrict__ sexp,
    float* __restrict__ h1) {
    int n = blockIdx.x;
    int tid = threadIdx.x;
    int lane = tid & 63, wave = tid >> 6;
    int beg = row_ptr[n], end = row_ptr[n + 1];
    __shared__ float al0[256], al1[256];
    __shared__ int src_s[256];
    __shared__ float den[2];
    if (tid < 2) den[tid] = 0.f;

    float fdv[8], aw[8];
    {
        uint4 q = *(const uint4*)(FD16 + (size_t)n * 512 + 8 * lane);
        unpack2(q.x, fdv[0], fdv[1]); unpack2(q.y, fdv[2], fdv[3]);
        unpack2(q.z, fdv[4], fdv[5]); unpack2(q.w, fdv[6], fdv[7]);
        float4 a0 = *(const float4*)(attn + 8 * lane);
        float4 a1 = *(const float4*)(attn + 8 * lane + 4);
        aw[0] = a0.x; aw[1] = a0.y; aw[2] = a0.z; aw[3] = a0.w;
        aw[4] = a1.x; aw[5] = a1.y; aw[6] = a1.z; aw[7] = a1.w;
    }
    __syncthreads();

    // ---- pass A: scores ----
    float dpriv = 0.f;
    for (int i = beg + wave; i < end; i += 4) {
        int s = csr_src[i];
        uint4 q = *(const uint4*)(FS16 + (size_t)s * 512 + 8 * lane);
        float f0, f1, p = 0.f;
        unpack2(q.x, f0, f1); p += lr(f0 + fdv[0]) * aw[0] + lr(f1 + fdv[1]) * aw[1];
        unpack2(q.y, f0, f1); p += lr(f0 + fdv[2]) * aw[2] + lr(f1 + fdv[3]) * aw[3];
        unpack2(q.z, f0, f1); p += lr(f0 + fdv[4]) * aw[4] + lr(f1 + fdv[5]) * aw[5];
        unpack2(q.w, f0, f1); p += lr(f0 + fdv[6]) * aw[6] + lr(f1 + fdv[7]) * aw[7];
#pragma unroll
        for (int off = 16; off > 0; off >>= 1) p += __shfl_down(p, off, 32);
        if ((lane & 31) == 0) {
            float ex = expf(p);
            sexp[2 * i + (lane >> 5)] = ex;
            dpriv += ex;
        }
    }
    if (lane == 0) atomicAdd(&den[0], dpriv);
    if (lane == 32) atomicAdd(&den[1], dpriv);
    __syncthreads();
    float inv0 = den[0] > 0.f ? 1.f / den[0] : 0.f;
    float inv1 = den[1] > 0.f ? 1.f / den[1] : 0.f;

    // ---- pass B: weighted aggregation ----
    float acc_a = 0.f, acc_b = 0.f;
    bool h0 = tid < 128;
    for (int cbeg = beg; cbeg < end; cbeg += 256) {
        int cnt = min(256, end - cbeg);
        if (tid < cnt) {
            int i = cbeg + tid;
            src_s[tid] = csr_src[i];
            al0[tid] = sexp[2 * i] * inv0;
            al1[tid] = sexp[2 * i + 1] * inv1;
        }
        __syncthreads();
        for (int j = 0; j < cnt; j++) {
            float al = h0 ? al0[j] : al1[j];
            unsigned int u = *(const unsigned int*)(FS16 + (size_t)src_s[j] * 512 + 2 * tid);
            float f0, f1; unpack2(u, f0, f1);
            acc_a += al * f0; acc_b += al * f1;
        }
        __syncthreads();
    }
    float e0 = acc_a > 0.f ? acc_a : expm1f(acc_a);
    float e1 = acc_b > 0.f ? acc_b : expm1f(acc_b);
    size_t base = (size_t)n * 512 + 2 * tid;
    float2 sk = *(float2*)(h1 + base);
    sk.x += e0; sk.y += e1;
    *(float2*)(h1 + base) = sk;
}

// ---------------- BatchNorm stats ----------------
__global__ __launch_bounds__(256) void bn_stats_kernel(const float* __restrict__ h1,
                                                       float* __restrict__ stats,
                                                       int rows_per_block) {
    int tid = threadIdx.x;
    int r0 = blockIdx.x * rows_per_block;
    int r1 = min(r0 + rows_per_block, N_NODES);
    float s0 = 0.f, q0 = 0.f, s1 = 0.f, q1 = 0.f;
    for (int r = r0; r < r1; r++) {
        float a = h1[(size_t)r * F2 + tid];
        float b = h1[(size_t)r * F2 + 256 + tid];
        s0 += a; q0 += a * a;
        s1 += b; q1 += b * b;
    }
    atomicAdd(&stats[tid], s0);
    atomicAdd(&stats[256 + tid], s1);
    atomicAdd(&stats[512 + tid], q0);
    atomicAdd(&stats[512 + 256 + tid], q1);
}

__global__ void bn_finalize_kernel(const float* __restrict__ stats,
                                   const float* __restrict__ gamma,
                                   const float* __restrict__ beta,
                                   float* __restrict__ bscale, float* __restrict__ bshift) {
    int c = threadIdx.x;  // 512 threads
    float mu = stats[c] / (float)N_NODES;
    float var = stats[512 + c] / (float)N_NODES - mu * mu;
    float sc = gamma[c] * rsqrtf(var + EPS_BN);
    bscale[c] = sc;
    bshift[c] = beta[c] - mu * sc;
}

// ---------------- gate scores ----------------
__global__ __launch_bounds__(256) void gate_kernel(const float* __restrict__ hr,
                                                   const float* __restrict__ wg,
                                                   const float* __restrict__ bg,
                                                   float* __restrict__ gate) {
    int n = blockIdx.x * 4 + (threadIdx.x >> 6);
    int lane = threadIdx.x & 63;
    const float4* row = (const float4*)(hr + (size_t)n * HID);
    const float4* w = (const float4*)wg;
    float4 a = row[lane], b = w[lane];
    float p = a.x * b.x + a.y * b.y + a.z * b.z + a.w * b.w;
#pragma unroll
    for (int off = 32; off > 0; off >>= 1) p += __shfl_down(p, off, 64);
    if (lane == 0) gate[n] = p + bg[0];
}

// ---------------- per-graph attention pooling ----------------
__device__ __forceinline__ int lower_bound_dev(const int* a, int n, int v) {
    int lo = 0, hi = n;
    while (lo < hi) {
        int mid = (lo + hi) >> 1;
        if (a[mid] < v) lo = mid + 1; else hi = mid;
    }
    return lo;
}

__global__ __launch_bounds__(256) void pool_kernel(const float* __restrict__ hr,
                                                   const float* __restrict__ gate,
                                                   const int* __restrict__ gids,
                                                   float* __restrict__ h_g) {
    int g = blockIdx.x;
    int tid = threadIdx.x;
    int start = lower_bound_dev(gids, N_NODES, g);
    int end = lower_bound_dev(gids, N_NODES, g + 1);
    __shared__ float red[256];
    __shared__ float wa[256];
    if (start >= end) { h_g[g * HID + tid] = 0.f; return; }
    float m = -3.4e38f;
    for (int i = start + tid; i < end; i += 256) m = fmaxf(m, gate[i]);
    red[tid] = m; __syncthreads();
    for (int off = 128; off > 0; off >>= 1) { if (tid < off) red[tid] = fmaxf(red[tid], red[tid + off]); __syncthreads(); }
    float gmax = red[0];
    __syncthreads();
    float se = 0.f;
    for (int i = start + tid; i < end; i += 256) se += expf(gate[i] - gmax);
    red[tid] = se; __syncthreads();
    for (int off = 128; off > 0; off >>= 1) { if (tid < off) red[tid] += red[tid + off]; __syncthreads(); }
    float ssum = red[0];
    __syncthreads();
    float acc = 0.f;
    for (int cbeg = start; cbeg < end; cbeg += 256) {
        int cnt = min(256, end - cbeg);
        if (tid < cnt) wa[tid] = expf(gate[cbeg + tid] - gmax);
        __syncthreads();
        for (int i = 0; i < cnt; i++) acc += wa[i] * hr[(size_t)(cbeg + i) * HID + tid];
        __syncthreads();
    }
    h_g[g * HID + tid] = acc / ssum;
}

// ---------------- classifier ----------------
__global__ __launch_bounds__(128) void classifier_kernel(
    const float* __restrict__ h_g, const float* __restrict__ W1, const float* __restrict__ b1,
    const float* __restrict__ W2, const float* __restrict__ b2, float* __restrict__ out) {
    int g = blockIdx.x;
    int tid = threadIdx.x;  // 128
    __shared__ float hg[256];
    __shared__ float z1[128];
    hg[tid] = h_g[g * HID + tid];
    hg[tid + 128] = h_g[g * HID + tid + 128];
    __syncthreads();
    float a = b1[tid];
#pragma unroll 8
    for (int k = 0; k < 256; k++) a += hg[k] * W1[k * 128 + tid];
    z1[tid] = a > 0.f ? a : 0.f;
    __syncthreads();
    if (tid < 10) {
        float o = b2[tid];
#pragma unroll 8
        for (int j = 0; j < 128; j++) o += z1[j] * W2[j * 10 + tid];
        out[g * 10 + tid] = o;
    }
}

// ---------------- launcher ----------------
extern "C" void kernel_launch(void* const* d_in, const int* in_sizes, int n_in,
                              void* d_out, int out_size, void* d_ws, size_t ws_size,
                              hipStream_t stream) {
    const float* feat   = (const float*)d_in[0];
    const int*   src    = (const int*)d_in[1];
    const int*   dst    = (const int*)d_in[2];
    const int*   gids   = (const int*)d_in[3];
    const float* W_src  = (const float*)d_in[4];
    const float* b_src  = (const float*)d_in[5];
    const float* W_dst  = (const float*)d_in[6];
    const float* b_dst  = (const float*)d_in[7];
    const float* attn   = (const float*)d_in[8];
    const float* W_skip = (const float*)d_in[9];
    const float* b_skip = (const float*)d_in[10];
    const float* gamma  = (const float*)d_in[11];
    const float* beta   = (const float*)d_in[12];
    const float* W_red  = (const float*)d_in[13];
    const float* b_red  = (const float*)d_in[14];
    const float* w_gate = (const float*)d_in[15];
    const float* b_gate = (const float*)d_in[16];
    const float* W1     = (const float*)d_in[17];
    const float* b1     = (const float*)d_in[18];
    const float* W2     = (const float*)d_in[19];
    const float* b2     = (const float*)d_in[20];
    float* out = (float*)d_out;

    char* p = (char*)d_ws;
    auto alloc = [&](size_t bytes) -> char* {
        char* r = p;
        p += (bytes + 255) & ~(size_t)255;
        return r;
    };
    u16*   FS16     = (u16*)alloc((size_t)N_NODES * F2 * 2);
    u16*   FD16     = (u16*)alloc((size_t)N_NODES * F2 * 2);
    float* h1       = (float*)alloc((size_t)N_NODES * F2 * 4);
    float* sexp     = (float*)alloc((size_t)N_EDGES * 2 * 4);
    float* gate     = (float*)alloc((size_t)N_NODES * 4);
    float* stats    = (float*)alloc(1024 * 4);
    float* bn_scale = (float*)alloc(512 * 4);
    float* bn_shift = (float*)alloc(512 * 4);
    float* h_g      = (float*)alloc((size_t)N_GRAPH * HID * 4);
    int* counts     = (int*)alloc((size_t)N_NODES * 4);
    int* row_ptr    = (int*)alloc((size_t)(N_NODES + 1) * 4);
    int* cursor     = (int*)alloc((size_t)N_NODES * 4);
    int* csr_src    = (int*)alloc((size_t)N_EDGES * 4);
    u16* Fhi        = (u16*)alloc((size_t)N_NODES * IN_DIM * 2);  // aliased as hr later
    u16* Flo        = (u16*)alloc((size_t)N_NODES * IN_DIM * 2);
    u16* Wthi       = (u16*)alloc((size_t)3 * 512 * 512 * 2);
    u16* Wtlo       = (u16*)alloc((size_t)3 * 512 * 512 * 2);
    // hr (20000*256*4 = 20.48 MB) aliases Fhi (20.48 MB): Fhi's last use
    // (gemm_mfma_fused) strictly precedes hr's first write (reducer GEMM).
    float* hr = (float*)Fhi;
    (void)ws_size; (void)in_sizes; (void)n_in; (void)out_size;

    // 1. init + input splits
    init_zero_kernel<<<(N_NODES + 255) / 256, 256, 0, stream>>>(counts, cursor, stats);
    split_feat_kernel<<<(N_NODES * IN_DIM / 8 + 255) / 256, 256, 0, stream>>>(
        feat, Fhi, Flo, N_NODES * IN_DIM / 8);
    split_wt_kernel<<<dim3(16, 16, 3), dim3(32, 8), 0, stream>>>(W_src, W_dst, W_skip, Wthi, Wtlo);

    // 2. fused MFMA GEMM: fs(bf16), fd(bf16), skip(fp32->h1)
    gemm_mfma_fused<<<dim3((N_NODES + 127) / 128, 12), 256, 0, stream>>>(
        Fhi, Flo, Wthi, Wtlo, b_src, b_dst, b_skip, FS16, FD16, h1);

    // 3-5. CSR by dst
    hist_kernel<<<(N_EDGES + 255) / 256, 256, 0, stream>>>(dst, counts);
    scan_kernel<<<1, 1024, 0, stream>>>(counts, row_ptr);
    scatter_kernel<<<(N_EDGES + 255) / 256, 256, 0, stream>>>(src, dst, row_ptr, cursor, csr_src);

    // 6. fused edge phase
    edge_fused_kernel<<<N_NODES, 256, 0, stream>>>(FS16, FD16, attn, csr_src, row_ptr, sexp, h1);

    // 7-8. BatchNorm stats -> scale/shift
    bn_stats_kernel<<<250, 256, 0, stream>>>(h1, stats, 80);
    bn_finalize_kernel<<<1, 512, 0, stream>>>(stats, gamma, beta, bn_scale, bn_shift);

    // 9. hr = BN(h1) @ W_red + b_red
    dim3 red_grid((N_NODES + 127) / 128, HID / 128);
    gemm128<true><<<red_grid, 256, 0, stream>>>(h1, W_red, b_red, hr, N_NODES, HID, bn_scale, bn_shift);

    // 10. gate
    gate_kernel<<<N_NODES / 4, 256, 0, stream>>>(hr, w_gate, b_gate, gate);

    // 11. per-graph pooling
    pool_kernel<<<N_GRAPH, 256, 0, stream>>>(hr, gate, gids, h_g);

    // 12. classifier
    classifier_kernel<<<N_GRAPH, 128, 0, stream>>>(h_g, W1, b1, W2, b2, out);
}

// Round 5
// 560.940 us; speedup vs baseline: 2.2756x; 1.2105x over previous
//
#include <hip/hip_runtime.h>
#include <math.h>

#define N_NODES 20000
#define N_EDGES 320000
#define N_GRAPH 64
#define IN_DIM  512
#define HID     256
#define F2      512   // HEADS*HID
#define EPS_BN  1e-5f
#define SLOPE   0.2f
#define SCAN_BLOCKS 79   // ceil(20000/256)

typedef unsigned short u16;
typedef __attribute__((ext_vector_type(8))) short bf16x8;
typedef __attribute__((ext_vector_type(4))) float floatx4;

// bf16 helpers: storage = upper 16 bits of fp32, round-to-nearest-even
__device__ __forceinline__ u16 bf_hi(float x) {
    unsigned int u = __float_as_uint(x);
    return (u16)((u + 0x7fffu + ((u >> 16) & 1u)) >> 16);
}
__device__ __forceinline__ float bf_val(u16 h) {
    return __uint_as_float((unsigned int)h << 16);
}
__device__ __forceinline__ void unpack2(unsigned int u, float& lo, float& hi) {
    lo = __uint_as_float(u << 16);
    hi = __uint_as_float(u & 0xffff0000u);
}
__device__ __forceinline__ float lr(float x) { return fmaxf(x, SLOPE * x); }

// ---------------- init: zero the ws regions that need it ----------------
__global__ void init_zero_kernel(int* counts, int* cursor, float* stats) {
    int i = blockIdx.x * blockDim.x + threadIdx.x;
    if (i < N_NODES) { counts[i] = 0; cursor[i] = 0; }
    if (i < 1024) stats[i] = 0.f;
}

// ---------------- split feat into bf16 hi/lo (row-major preserved) ------
__global__ __launch_bounds__(256) void split_feat_kernel(
    const float* __restrict__ X, u16* __restrict__ Hi, u16* __restrict__ Lo,
    int total8) {
    int i = blockIdx.x * 256 + threadIdx.x;
    if (i >= total8) return;
    size_t base = (size_t)i * 8;
    float4 x0 = *(const float4*)(X + base);
    float4 x1 = *(const float4*)(X + base + 4);
    float xs[8] = {x0.x, x0.y, x0.z, x0.w, x1.x, x1.y, x1.z, x1.w};
    union { u16 s[8]; uint4 v; } h, l;
#pragma unroll
    for (int j = 0; j < 8; j++) {
        u16 hh = bf_hi(xs[j]);
        h.s[j] = hh;
        l.s[j] = bf_hi(xs[j] - bf_val(hh));
    }
    *(uint4*)(Hi + base) = h.v;
    *(uint4*)(Lo + base) = l.v;
}

// --- transpose + split 4 weights: W[k][n] -> Wt[n][k] hi/lo -------------
// z=0..2: 512x512 (W_src,W_dst,W_skip); z=3: W_red 512x256.
__global__ __launch_bounds__(256) void split_wt_kernel(
    const float* __restrict__ Ws, const float* __restrict__ Wd,
    const float* __restrict__ Wk, const float* __restrict__ Wr,
    u16* __restrict__ Hi, u16* __restrict__ Lo) {
    __shared__ float t[32][33];
    int w = blockIdx.z;
    int ncols = (w == 3) ? 256 : 512;
    int n0 = blockIdx.y * 32;
    if (n0 >= ncols) return;
    const float* W = (w == 0) ? Ws : ((w == 1) ? Wd : ((w == 2) ? Wk : Wr));
    size_t obase = (w == 3) ? (size_t)3 * 512 * 512 : (size_t)w * 512 * 512;
    int k0 = blockIdx.x * 32;
    int tx = threadIdx.x, ty = threadIdx.y;  // 32 x 8
#pragma unroll
    for (int i = 0; i < 4; i++)
        t[ty * 4 + i][tx] = W[(size_t)(k0 + ty * 4 + i) * ncols + n0 + tx];
    __syncthreads();
#pragma unroll
    for (int i = 0; i < 4; i++) {
        float x = t[tx][ty * 4 + i];  // = W[k0+tx][n0+ty*4+i]
        u16 hh = bf_hi(x);
        size_t o = obase + (size_t)(n0 + ty * 4 + i) * 512 + k0 + tx;
        Hi[o] = hh;
        Lo[o] = bf_hi(x - bf_val(hh));
    }
}

// ------------------- MFMA GEMM template ---------------------------------
// C[N,M] = A[N,512] @ B[512,M] + bias.  B pre-transposed+split: Bt[n][k].
// TERMS=1: plain bf16 (Ahi x Bhi).  TERMS=3: split hi/lo, fp32-class.
// USE_BN: A is fp32; y = A*scale+shift applied + split at staging (TERMS=3).
// 128x128 C-tile/block, 4 waves each 64x64 (4x4 of 16x16x32 MFMA tiles).
template <int TERMS, bool OUT_BF16, bool USE_BN>
__global__ __launch_bounds__(256) void gemm_mfma(
    const u16* __restrict__ Ahi, const u16* __restrict__ Alo,
    const float* __restrict__ Af,
    const u16* __restrict__ Bhi, const u16* __restrict__ Blo,
    const float* __restrict__ bias, void* __restrict__ Cv,
    int Nrows, int M,
    const float* __restrict__ bscale, const float* __restrict__ bshift) {
    __shared__ u16 AsHi[128 * 40];
    __shared__ u16 AsLo[(TERMS == 3) ? 128 * 40 : 8];
    __shared__ float sBN[USE_BN ? 1024 : 2];
    int tid = threadIdx.x;
    int row0 = blockIdx.x * 128;
    int col0 = blockIdx.y * 128;
    int lane = tid & 63, wave = tid >> 6;
    int wm = (wave & 1) * 64, wn = (wave >> 1) * 64;
    int quad = lane >> 4, l16 = lane & 15;

    if (USE_BN) {
        sBN[tid] = bscale[tid]; sBN[256 + tid] = bscale[256 + tid];
        sBN[512 + tid] = bshift[tid]; sBN[768 + tid] = bshift[256 + tid];
        __syncthreads();
    }

    // staging map: thread t -> row t>>1, 16-elem half (t&1)*16
    int sr = tid >> 1, sh = (tid & 1) * 16;
    int grow = row0 + sr;
    bool ok = grow < Nrows;
    u16* sA_hi = &AsHi[sr * 40 + sh];
    u16* sA_lo = &AsLo[(TERMS == 3) ? sr * 40 + sh : 0];

    floatx4 acc[4][4];
#pragma unroll
    for (int i = 0; i < 4; i++)
#pragma unroll
        for (int j = 0; j < 4; j++) acc[i][j] = (floatx4){0.f, 0.f, 0.f, 0.f};

    for (int k0 = 0; k0 < 512; k0 += 32) {
        uint4 a0 = make_uint4(0, 0, 0, 0), a1 = a0, q0 = a0, q1 = a0;
        if (USE_BN) {
            float v[16];
            if (ok) {
                const float* g = Af + (size_t)grow * 512 + k0 + sh;
                *(float4*)&v[0]  = *(const float4*)(g);
                *(float4*)&v[4]  = *(const float4*)(g + 4);
                *(float4*)&v[8]  = *(const float4*)(g + 8);
                *(float4*)&v[12] = *(const float4*)(g + 12);
            } else {
#pragma unroll
                for (int j = 0; j < 16; j++) v[j] = 0.f;
            }
            union { u16 s[8]; uint4 u; } h0_, h1_, l0_, l1_;
#pragma unroll
            for (int j = 0; j < 16; j++) {
                int kc = k0 + sh + j;
                float x = v[j] * sBN[kc] + sBN[512 + kc];
                u16 hh = bf_hi(x);
                u16 ll = bf_hi(x - bf_val(hh));
                if (j < 8) { h0_.s[j] = hh; l0_.s[j] = ll; }
                else       { h1_.s[j - 8] = hh; l1_.s[j - 8] = ll; }
            }
            a0 = h0_.u; a1 = h1_.u; q0 = l0_.u; q1 = l1_.u;
        } else if (ok) {
            const u16* g = Ahi + (size_t)grow * 512 + k0 + sh;
            a0 = *(const uint4*)(g);
            a1 = *(const uint4*)(g + 8);
            if (TERMS == 3) {
                const u16* gl = Alo + (size_t)grow * 512 + k0 + sh;
                q0 = *(const uint4*)(gl);
                q1 = *(const uint4*)(gl + 8);
            }
        }
        union { uint4 u; bf16x8 v; } bh[4], bl[4];
#pragma unroll
        for (int nt = 0; nt < 4; nt++) {
            size_t off = (size_t)(col0 + wn + nt * 16 + l16) * 512 + k0 + quad * 8;
            bh[nt].u = *(const uint4*)(Bhi + off);
            if (TERMS == 3) bl[nt].u = *(const uint4*)(Blo + off);
        }
        __syncthreads();  // previous iteration's LDS reads complete
        *(uint4*)(sA_hi + 0) = a0;
        *(uint4*)(sA_hi + 8) = a1;
        if (TERMS == 3) {
            *(uint4*)(sA_lo + 0) = q0;
            *(uint4*)(sA_lo + 8) = q1;
        }
        __syncthreads();
#pragma unroll
        for (int mt = 0; mt < 4; mt++) {
            int me = (wm + mt * 16 + l16) * 40 + quad * 8;
            bf16x8 ah = *(const bf16x8*)&AsHi[me];
#pragma unroll
            for (int nt = 0; nt < 4; nt++)
                acc[mt][nt] = __builtin_amdgcn_mfma_f32_16x16x32_bf16(ah, bh[nt].v, acc[mt][nt], 0, 0, 0);
            if (TERMS == 3) {
                bf16x8 al = *(const bf16x8*)&AsLo[me];
#pragma unroll
                for (int nt = 0; nt < 4; nt++) {
                    acc[mt][nt] = __builtin_amdgcn_mfma_f32_16x16x32_bf16(ah, bl[nt].v, acc[mt][nt], 0, 0, 0);
                    acc[mt][nt] = __builtin_amdgcn_mfma_f32_16x16x32_bf16(al, bh[nt].v, acc[mt][nt], 0, 0, 0);
                }
            }
        }
    }

    float bv[4];
#pragma unroll
    for (int nt = 0; nt < 4; nt++) bv[nt] = bias[col0 + wn + nt * 16 + l16];
#pragma unroll
    for (int mt = 0; mt < 4; mt++) {
#pragma unroll
        for (int r = 0; r < 4; r++) {
            int m = row0 + wm + mt * 16 + quad * 4 + r;
            if (m < Nrows) {
#pragma unroll
                for (int nt = 0; nt < 4; nt++) {
                    int n = col0 + wn + nt * 16 + l16;
                    float vv = acc[mt][nt][r] + bv[nt];
                    if (OUT_BF16) ((u16*)Cv)[(size_t)m * M + n] = bf_hi(vv);
                    else          ((float*)Cv)[(size_t)m * M + n] = vv;
                }
            }
        }
    }
}

// ---------------- CSR build ----------------
__global__ void hist_kernel(const int* __restrict__ dst, int* __restrict__ counts) {
    int e = blockIdx.x * blockDim.x + threadIdx.x;
    if (e < N_EDGES) atomicAdd(&counts[dst[e]], 1);
}

// two-level scan: per-block inclusive scan + block sums, then fixup
__global__ __launch_bounds__(256) void scan_local_kernel(
    const int* __restrict__ counts, int* __restrict__ row_ptr, int* __restrict__ bsum) {
    __shared__ int buf[256];
    int b = blockIdx.x, tid = threadIdx.x;
    int i = b * 256 + tid;
    buf[tid] = (i < N_NODES) ? counts[i] : 0;
    __syncthreads();
    for (int off = 1; off < 256; off <<= 1) {
        int t = (tid >= off) ? buf[tid - off] : 0;
        __syncthreads();
        buf[tid] += t;
        __syncthreads();
    }
    if (i < N_NODES) row_ptr[i + 1] = buf[tid];
    if (tid == 255) bsum[b] = buf[255];
}

__global__ __launch_bounds__(256) void scan_fixup_kernel(
    const int* __restrict__ bsum, int* __restrict__ row_ptr) {
    __shared__ int red[256];
    int b = blockIdx.x, tid = threadIdx.x;
    red[tid] = (tid < b) ? bsum[tid] : 0;
    __syncthreads();
    for (int off = 128; off > 0; off >>= 1) {
        if (tid < off) red[tid] += red[tid + off];
        __syncthreads();
    }
    int offset = red[0];
    int i = b * 256 + tid;
    if (i < N_NODES) row_ptr[i + 1] += offset;
    if (b == 0 && tid == 0) row_ptr[0] = 0;
}

__global__ void scatter_kernel(const int* __restrict__ src, const int* __restrict__ dst,
                               const int* __restrict__ row_ptr,
                               int* __restrict__ cursor, int* __restrict__ csr_src) {
    int e = blockIdx.x * blockDim.x + threadIdx.x;
    if (e < N_EDGES) {
        int d = dst[e];
        int pos = atomicAdd(&cursor[d], 1);
        csr_src[row_ptr[d] + pos] = src[e];
    }
}

// -------- fused edge phase: scores + softmax + aggregation + ELU + skip --
__global__ __launch_bounds__(256) void edge_fused_kernel(
    const u16* __restrict__ FS16, const u16* __restrict__ FD16,
    const float* __restrict__ attn, const int* __restrict__ csr_src,
    const int* __restrict__ row_ptr, float* __restrict__ sexp,
    float* __restrict__ h1) {
    int n = blockIdx.x;
    int tid = threadIdx.x;
    int lane = tid & 63, wave = tid >> 6;
    int beg = row_ptr[n], end = row_ptr[n + 1];
    __shared__ float al0[256], al1[256];
    __shared__ int src_s[256];
    __shared__ float den[2];
    if (tid < 2) den[tid] = 0.f;

    float fdv[8], aw[8];
    {
        uint4 q = *(const uint4*)(FD16 + (size_t)n * 512 + 8 * lane);
        unpack2(q.x, fdv[0], fdv[1]); unpack2(q.y, fdv[2], fdv[3]);
        unpack2(q.z, fdv[4], fdv[5]); unpack2(q.w, fdv[6], fdv[7]);
        float4 a0 = *(const float4*)(attn + 8 * lane);
        float4 a1 = *(const float4*)(attn + 8 * lane + 4);
        aw[0] = a0.x; aw[1] = a0.y; aw[2] = a0.z; aw[3] = a0.w;
        aw[4] = a1.x; aw[5] = a1.y; aw[6] = a1.z; aw[7] = a1.w;
    }
    __syncthreads();

    // ---- pass A: scores ----
    float dpriv = 0.f;
    for (int i = beg + wave; i < end; i += 4) {
        int s = csr_src[i];
        uint4 q = *(const uint4*)(FS16 + (size_t)s * 512 + 8 * lane);
        float f0, f1, p = 0.f;
        unpack2(q.x, f0, f1); p += lr(f0 + fdv[0]) * aw[0] + lr(f1 + fdv[1]) * aw[1];
        unpack2(q.y, f0, f1); p += lr(f0 + fdv[2]) * aw[2] + lr(f1 + fdv[3]) * aw[3];
        unpack2(q.z, f0, f1); p += lr(f0 + fdv[4]) * aw[4] + lr(f1 + fdv[5]) * aw[5];
        unpack2(q.w, f0, f1); p += lr(f0 + fdv[6]) * aw[6] + lr(f1 + fdv[7]) * aw[7];
#pragma unroll
        for (int off = 16; off > 0; off >>= 1) p += __shfl_down(p, off, 32);
        if ((lane & 31) == 0) {
            float ex = expf(p);  // shift-invariant: no max pass needed
            sexp[2 * i + (lane >> 5)] = ex;
            dpriv += ex;
        }
    }
    if (lane == 0) atomicAdd(&den[0], dpriv);
    if (lane == 32) atomicAdd(&den[1], dpriv);
    __syncthreads();
    float inv0 = den[0] > 0.f ? 1.f / den[0] : 0.f;
    float inv1 = den[1] > 0.f ? 1.f / den[1] : 0.f;

    // ---- pass B: weighted aggregation ----
    float acc_a = 0.f, acc_b = 0.f;
    bool h0 = tid < 128;
    for (int cbeg = beg; cbeg < end; cbeg += 256) {
        int cnt = min(256, end - cbeg);
        if (tid < cnt) {
            int i = cbeg + tid;
            src_s[tid] = csr_src[i];
            al0[tid] = sexp[2 * i] * inv0;
            al1[tid] = sexp[2 * i + 1] * inv1;
        }
        __syncthreads();
        for (int j = 0; j < cnt; j++) {
            float al = h0 ? al0[j] : al1[j];
            unsigned int u = *(const unsigned int*)(FS16 + (size_t)src_s[j] * 512 + 2 * tid);
            float f0, f1; unpack2(u, f0, f1);
            acc_a += al * f0; acc_b += al * f1;
        }
        __syncthreads();
    }
    float e0 = acc_a > 0.f ? acc_a : expm1f(acc_a);
    float e1 = acc_b > 0.f ? acc_b : expm1f(acc_b);
    size_t base = (size_t)n * 512 + 2 * tid;
    float2 sk = *(float2*)(h1 + base);
    sk.x += e0; sk.y += e1;
    *(float2*)(h1 + base) = sk;
}

// ---------------- BatchNorm stats ----------------
__global__ __launch_bounds__(256) void bn_stats_kernel(const float* __restrict__ h1,
                                                       float* __restrict__ stats,
                                                       int rows_per_block) {
    int tid = threadIdx.x;
    int r0 = blockIdx.x * rows_per_block;
    int r1 = min(r0 + rows_per_block, N_NODES);
    float s0 = 0.f, q0 = 0.f, s1 = 0.f, q1 = 0.f;
    for (int r = r0; r < r1; r++) {
        float a = h1[(size_t)r * F2 + tid];
        float b = h1[(size_t)r * F2 + 256 + tid];
        s0 += a; q0 += a * a;
        s1 += b; q1 += b * b;
    }
    atomicAdd(&stats[tid], s0);
    atomicAdd(&stats[256 + tid], s1);
    atomicAdd(&stats[512 + tid], q0);
    atomicAdd(&stats[512 + 256 + tid], q1);
}

__global__ void bn_finalize_kernel(const float* __restrict__ stats,
                                   const float* __restrict__ gamma,
                                   const float* __restrict__ beta,
                                   float* __restrict__ bscale, float* __restrict__ bshift) {
    int c = threadIdx.x;  // 512 threads
    float mu = stats[c] / (float)N_NODES;
    float var = stats[512 + c] / (float)N_NODES - mu * mu;
    float sc = gamma[c] * rsqrtf(var + EPS_BN);
    bscale[c] = sc;
    bshift[c] = beta[c] - mu * sc;
}

// ---------------- gate scores ----------------
__global__ __launch_bounds__(256) void gate_kernel(const float* __restrict__ hr,
                                                   const float* __restrict__ wg,
                                                   const float* __restrict__ bg,
                                                   float* __restrict__ gate) {
    int n = blockIdx.x * 4 + (threadIdx.x >> 6);
    int lane = threadIdx.x & 63;
    const float4* row = (const float4*)(hr + (size_t)n * HID);
    const float4* w = (const float4*)wg;
    float4 a = row[lane], b = w[lane];
    float p = a.x * b.x + a.y * b.y + a.z * b.z + a.w * b.w;
#pragma unroll
    for (int off = 32; off > 0; off >>= 1) p += __shfl_down(p, off, 64);
    if (lane == 0) gate[n] = p + bg[0];
}

// ---------------- per-graph attention pooling ----------------
__device__ __forceinline__ int lower_bound_dev(const int* a, int n, int v) {
    int lo = 0, hi = n;
    while (lo < hi) {
        int mid = (lo + hi) >> 1;
        if (a[mid] < v) lo = mid + 1; else hi = mid;
    }
    return lo;
}

__global__ __launch_bounds__(256) void pool_kernel(const float* __restrict__ hr,
                                                   const float* __restrict__ gate,
                                                   const int* __restrict__ gids,
                                                   float* __restrict__ h_g) {
    int g = blockIdx.x;
    int tid = threadIdx.x;
    int start = lower_bound_dev(gids, N_NODES, g);
    int end = lower_bound_dev(gids, N_NODES, g + 1);
    __shared__ float red[256];
    __shared__ float wa[256];
    if (start >= end) { h_g[g * HID + tid] = 0.f; return; }
    float m = -3.4e38f;
    for (int i = start + tid; i < end; i += 256) m = fmaxf(m, gate[i]);
    red[tid] = m; __syncthreads();
    for (int off = 128; off > 0; off >>= 1) { if (tid < off) red[tid] = fmaxf(red[tid], red[tid + off]); __syncthreads(); }
    float gmax = red[0];
    __syncthreads();
    float se = 0.f;
    for (int i = start + tid; i < end; i += 256) se += expf(gate[i] - gmax);
    red[tid] = se; __syncthreads();
    for (int off = 128; off > 0; off >>= 1) { if (tid < off) red[tid] += red[tid + off]; __syncthreads(); }
    float ssum = red[0];
    __syncthreads();
    float acc = 0.f;
    for (int cbeg = start; cbeg < end; cbeg += 256) {
        int cnt = min(256, end - cbeg);
        if (tid < cnt) wa[tid] = expf(gate[cbeg + tid] - gmax);
        __syncthreads();
        for (int i = 0; i < cnt; i++) acc += wa[i] * hr[(size_t)(cbeg + i) * HID + tid];
        __syncthreads();
    }
    h_g[g * HID + tid] = acc / ssum;
}

// ---------------- classifier ----------------
__global__ __launch_bounds__(128) void classifier_kernel(
    const float* __restrict__ h_g, const float* __restrict__ W1, const float* __restrict__ b1,
    const float* __restrict__ W2, const float* __restrict__ b2, float* __restrict__ out) {
    int g = blockIdx.x;
    int tid = threadIdx.x;  // 128
    __shared__ float hg[256];
    __shared__ float z1[128];
    hg[tid] = h_g[g * HID + tid];
    hg[tid + 128] = h_g[g * HID + tid + 128];
    __syncthreads();
    float a = b1[tid];
#pragma unroll 8
    for (int k = 0; k < 256; k++) a += hg[k] * W1[k * 128 + tid];
    z1[tid] = a > 0.f ? a : 0.f;
    __syncthreads();
    if (tid < 10) {
        float o = b2[tid];
#pragma unroll 8
        for (int j = 0; j < 128; j++) o += z1[j] * W2[j * 10 + tid];
        out[g * 10 + tid] = o;
    }
}

// ---------------- launcher ----------------
extern "C" void kernel_launch(void* const* d_in, const int* in_sizes, int n_in,
                              void* d_out, int out_size, void* d_ws, size_t ws_size,
                              hipStream_t stream) {
    const float* feat   = (const float*)d_in[0];
    const int*   src    = (const int*)d_in[1];
    const int*   dst    = (const int*)d_in[2];
    const int*   gids   = (const int*)d_in[3];
    const float* W_src  = (const float*)d_in[4];
    const float* b_src  = (const float*)d_in[5];
    const float* W_dst  = (const float*)d_in[6];
    const float* b_dst  = (const float*)d_in[7];
    const float* attn   = (const float*)d_in[8];
    const float* W_skip = (const float*)d_in[9];
    const float* b_skip = (const float*)d_in[10];
    const float* gamma  = (const float*)d_in[11];
    const float* beta   = (const float*)d_in[12];
    const float* W_red  = (const float*)d_in[13];
    const float* b_red  = (const float*)d_in[14];
    const float* w_gate = (const float*)d_in[15];
    const float* b_gate = (const float*)d_in[16];
    const float* W1     = (const float*)d_in[17];
    const float* b1     = (const float*)d_in[18];
    const float* W2     = (const float*)d_in[19];
    const float* b2     = (const float*)d_in[20];
    float* out = (float*)d_out;

    char* p = (char*)d_ws;
    auto alloc = [&](size_t bytes) -> char* {
        char* r = p;
        p += (bytes + 255) & ~(size_t)255;
        return r;
    };
    u16*   FS16     = (u16*)alloc((size_t)N_NODES * F2 * 2);
    u16*   FD16     = (u16*)alloc((size_t)N_NODES * F2 * 2);
    float* h1       = (float*)alloc((size_t)N_NODES * F2 * 4);
    float* sexp     = (float*)alloc((size_t)N_EDGES * 2 * 4);
    float* gate     = (float*)alloc((size_t)N_NODES * 4);
    float* stats    = (float*)alloc(1024 * 4);
    float* bn_scale = (float*)alloc(512 * 4);
    float* bn_shift = (float*)alloc(512 * 4);
    float* h_g      = (float*)alloc((size_t)N_GRAPH * HID * 4);
    int* counts     = (int*)alloc((size_t)N_NODES * 4);
    int* row_ptr    = (int*)alloc((size_t)(N_NODES + 1) * 4);
    int* cursor     = (int*)alloc((size_t)N_NODES * 4);
    int* csr_src    = (int*)alloc((size_t)N_EDGES * 4);
    int* bsum       = (int*)alloc((size_t)SCAN_BLOCKS * 4);
    u16* Fhi        = (u16*)alloc((size_t)N_NODES * IN_DIM * 2);  // aliased as hr later
    u16* Flo        = (u16*)alloc((size_t)N_NODES * IN_DIM * 2);
    u16* Wthi       = (u16*)alloc(((size_t)3 * 512 * 512 + 256 * 512) * 2);
    u16* Wtlo       = (u16*)alloc(((size_t)3 * 512 * 512 + 256 * 512) * 2);
    // hr (20000*256*4 = 20.48 MB) aliases Fhi (20.48 MB): Fhi's last use
    // (skip GEMM) strictly precedes hr's first write (reducer GEMM).
    float* hr = (float*)Fhi;
    (void)ws_size; (void)in_sizes; (void)n_in; (void)out_size;

    const size_t WSZ = (size_t)512 * 512;

    // 1. init + input splits
    init_zero_kernel<<<(N_NODES + 255) / 256, 256, 0, stream>>>(counts, cursor, stats);
    split_feat_kernel<<<(N_NODES * IN_DIM / 8 + 255) / 256, 256, 0, stream>>>(
        feat, Fhi, Flo, N_NODES * IN_DIM / 8);
    split_wt_kernel<<<dim3(16, 16, 4), dim3(32, 8), 0, stream>>>(
        W_src, W_dst, W_skip, W_red, Wthi, Wtlo);

    // 2. input GEMMs: fs/fd 1-term bf16 (outputs are bf16 anyway),
    //    skip 3-term split (feeds fp32 BN path)
    dim3 g512((N_NODES + 127) / 128, 4);
    gemm_mfma<1, true, false><<<g512, 256, 0, stream>>>(
        Fhi, nullptr, nullptr, Wthi + 0 * WSZ, nullptr, b_src, FS16, N_NODES, F2, nullptr, nullptr);
    gemm_mfma<1, true, false><<<g512, 256, 0, stream>>>(
        Fhi, nullptr, nullptr, Wthi + 1 * WSZ, nullptr, b_dst, FD16, N_NODES, F2, nullptr, nullptr);
    gemm_mfma<3, false, false><<<g512, 256, 0, stream>>>(
        Fhi, Flo, nullptr, Wthi + 2 * WSZ, Wtlo + 2 * WSZ, b_skip, h1, N_NODES, F2, nullptr, nullptr);

    // 3-5. CSR by dst (two-level scan)
    hist_kernel<<<(N_EDGES + 255) / 256, 256, 0, stream>>>(dst, counts);
    scan_local_kernel<<<SCAN_BLOCKS, 256, 0, stream>>>(counts, row_ptr, bsum);
    scan_fixup_kernel<<<SCAN_BLOCKS, 256, 0, stream>>>(bsum, row_ptr);
    scatter_kernel<<<(N_EDGES + 255) / 256, 256, 0, stream>>>(src, dst, row_ptr, cursor, csr_src);

    // 6. fused edge phase
    edge_fused_kernel<<<N_NODES, 256, 0, stream>>>(FS16, FD16, attn, csr_src, row_ptr, sexp, h1);

    // 7-8. BatchNorm stats -> scale/shift
    bn_stats_kernel<<<250, 256, 0, stream>>>(h1, stats, 80);
    bn_finalize_kernel<<<1, 512, 0, stream>>>(stats, gamma, beta, bn_scale, bn_shift);

    // 9. hr = BN(h1) @ W_red + b_red  (MFMA, BN fold + split at staging)
    dim3 g256((N_NODES + 127) / 128, 2);
    gemm_mfma<3, false, true><<<g256, 256, 0, stream>>>(
        nullptr, nullptr, h1, Wthi + 3 * WSZ, Wtlo + 3 * WSZ, b_red, hr, N_NODES, HID,
        bn_scale, bn_shift);

    // 10. gate
    gate_kernel<<<N_NODES / 4, 256, 0, stream>>>(hr, w_gate, b_gate, gate);

    // 11. per-graph pooling
    pool_kernel<<<N_GRAPH, 256, 0, stream>>>(hr, gate, gids, h_g);

    // 12. classifier
    classifier_kernel<<<N_GRAPH, 128, 0, stream>>>(h_g, W1, b1, W2, b2, out);
}

// Round 6
// 457.586 us; speedup vs baseline: 2.7896x; 1.2259x over previous
//
#include <hip/hip_runtime.h>
#include <math.h>

#define N_NODES 20000
#define N_EDGES 320000
#define N_GRAPH 64
#define IN_DIM  512
#define HID     256
#define F2      512   // HEADS*HID
#define EPS_BN  1e-5f
#define SLOPE   0.2f
#define SCAN_BLOCKS 79   // ceil(20000/256)
#define ECAP 1024        // max in-degree held in LDS (fallback path beyond)

typedef unsigned short u16;
typedef __attribute__((ext_vector_type(8))) short bf16x8;
typedef __attribute__((ext_vector_type(4))) float floatx4;

// bf16 helpers: storage = upper 16 bits of fp32, round-to-nearest-even
__device__ __forceinline__ u16 bf_hi(float x) {
    unsigned int u = __float_as_uint(x);
    return (u16)((u + 0x7fffu + ((u >> 16) & 1u)) >> 16);
}
__device__ __forceinline__ float bf_val(u16 h) {
    return __uint_as_float((unsigned int)h << 16);
}
__device__ __forceinline__ void unpack2(unsigned int u, float& lo, float& hi) {
    lo = __uint_as_float(u << 16);
    hi = __uint_as_float(u & 0xffff0000u);
}
__device__ __forceinline__ float lr(float x) { return fmaxf(x, SLOPE * x); }

// ---------------- init: zero the ws regions that need it ----------------
__global__ void init_zero_kernel(int* counts, int* cursor, float* stats,
                                 float* h_gnum, float* gden) {
    int i = blockIdx.x * blockDim.x + threadIdx.x;
    if (i < N_NODES) { counts[i] = 0; cursor[i] = 0; }
    if (i < 1024) stats[i] = 0.f;
    if (i < N_GRAPH * HID) h_gnum[i] = 0.f;
    if (i < N_GRAPH) gden[i] = 0.f;
}

// ---------------- feat -> bf16 (row-major preserved) --------------------
__global__ __launch_bounds__(256) void split_feat_kernel(
    const float* __restrict__ X, u16* __restrict__ Hi, int total8) {
    int i = blockIdx.x * 256 + threadIdx.x;
    if (i >= total8) return;
    size_t base = (size_t)i * 8;
    float4 x0 = *(const float4*)(X + base);
    float4 x1 = *(const float4*)(X + base + 4);
    float xs[8] = {x0.x, x0.y, x0.z, x0.w, x1.x, x1.y, x1.z, x1.w};
    union { u16 s[8]; uint4 v; } h;
#pragma unroll
    for (int j = 0; j < 8; j++) h.s[j] = bf_hi(xs[j]);
    *(uint4*)(Hi + base) = h.v;
}

// --- transpose + split 4 weights: W[k][n] -> Wt[n][k] hi/lo -------------
// z=0..2: 512x512 (W_src,W_dst,W_skip); z=3: W_red 512x256.
__global__ __launch_bounds__(256) void split_wt_kernel(
    const float* __restrict__ Ws, const float* __restrict__ Wd,
    const float* __restrict__ Wk, const float* __restrict__ Wr,
    u16* __restrict__ Hi, u16* __restrict__ Lo) {
    __shared__ float t[32][33];
    int w = blockIdx.z;
    int ncols = (w == 3) ? 256 : 512;
    int n0 = blockIdx.y * 32;
    if (n0 >= ncols) return;
    const float* W = (w == 0) ? Ws : ((w == 1) ? Wd : ((w == 2) ? Wk : Wr));
    size_t obase = (size_t)w * 512 * 512;
    int k0 = blockIdx.x * 32;
    int tx = threadIdx.x, ty = threadIdx.y;  // 32 x 8
#pragma unroll
    for (int i = 0; i < 4; i++)
        t[ty * 4 + i][tx] = W[(size_t)(k0 + ty * 4 + i) * ncols + n0 + tx];
    __syncthreads();
#pragma unroll
    for (int i = 0; i < 4; i++) {
        float x = t[tx][ty * 4 + i];  // = W[k0+tx][n0+ty*4+i]
        u16 hh = bf_hi(x);
        size_t o = obase + (size_t)(n0 + ty * 4 + i) * 512 + k0 + tx;
        Hi[o] = hh;
        Lo[o] = bf_hi(x - bf_val(hh));
    }
}

// ------------------- MFMA GEMM template ---------------------------------
// C[N,M] = A[N,512] @ B[512,M] + bias.  B pre-transposed+split: Bt[n][k].
// TERMS=1: plain bf16 (Ahi x Bhi).  TERMS=3: split hi/lo, fp32-class.
// USE_BN: A is fp32; y = A*scale+shift applied + split at staging (TERMS=3).
template <int TERMS, bool OUT_BF16, bool USE_BN>
__global__ __launch_bounds__(256) void gemm_mfma(
    const u16* __restrict__ Ahi, const float* __restrict__ Af,
    const u16* __restrict__ Bhi, const u16* __restrict__ Blo,
    const float* __restrict__ bias, void* __restrict__ Cv,
    int Nrows, int M,
    const float* __restrict__ bscale, const float* __restrict__ bshift) {
    __shared__ u16 AsHi[128 * 40];
    __shared__ u16 AsLo[(TERMS == 3) ? 128 * 40 : 8];
    __shared__ float sBN[USE_BN ? 1024 : 2];
    int tid = threadIdx.x;
    int row0 = blockIdx.x * 128;
    int col0 = blockIdx.y * 128;
    int lane = tid & 63, wave = tid >> 6;
    int wm = (wave & 1) * 64, wn = (wave >> 1) * 64;
    int quad = lane >> 4, l16 = lane & 15;

    if (USE_BN) {
        sBN[tid] = bscale[tid]; sBN[256 + tid] = bscale[256 + tid];
        sBN[512 + tid] = bshift[tid]; sBN[768 + tid] = bshift[256 + tid];
        __syncthreads();
    }

    int sr = tid >> 1, sh = (tid & 1) * 16;
    int grow = row0 + sr;
    bool ok = grow < Nrows;
    u16* sA_hi = &AsHi[sr * 40 + sh];
    u16* sA_lo = &AsLo[(TERMS == 3) ? sr * 40 + sh : 0];

    floatx4 acc[4][4];
#pragma unroll
    for (int i = 0; i < 4; i++)
#pragma unroll
        for (int j = 0; j < 4; j++) acc[i][j] = (floatx4){0.f, 0.f, 0.f, 0.f};

    for (int k0 = 0; k0 < 512; k0 += 32) {
        uint4 a0 = make_uint4(0, 0, 0, 0), a1 = a0, q0 = a0, q1 = a0;
        if (USE_BN) {
            float v[16];
            if (ok) {
                const float* g = Af + (size_t)grow * 512 + k0 + sh;
                *(float4*)&v[0]  = *(const float4*)(g);
                *(float4*)&v[4]  = *(const float4*)(g + 4);
                *(float4*)&v[8]  = *(const float4*)(g + 8);
                *(float4*)&v[12] = *(const float4*)(g + 12);
            } else {
#pragma unroll
                for (int j = 0; j < 16; j++) v[j] = 0.f;
            }
            union { u16 s[8]; uint4 u; } h0_, h1_, l0_, l1_;
#pragma unroll
            for (int j = 0; j < 16; j++) {
                int kc = k0 + sh + j;
                float x = v[j] * sBN[kc] + sBN[512 + kc];
                u16 hh = bf_hi(x);
                u16 ll = bf_hi(x - bf_val(hh));
                if (j < 8) { h0_.s[j] = hh; l0_.s[j] = ll; }
                else       { h1_.s[j - 8] = hh; l1_.s[j - 8] = ll; }
            }
            a0 = h0_.u; a1 = h1_.u; q0 = l0_.u; q1 = l1_.u;
        } else if (ok) {
            const u16* g = Ahi + (size_t)grow * 512 + k0 + sh;
            a0 = *(const uint4*)(g);
            a1 = *(const uint4*)(g + 8);
        }
        union { uint4 u; bf16x8 v; } bh[4], bl[4];
#pragma unroll
        for (int nt = 0; nt < 4; nt++) {
            size_t off = (size_t)(col0 + wn + nt * 16 + l16) * 512 + k0 + quad * 8;
            bh[nt].u = *(const uint4*)(Bhi + off);
            if (TERMS == 3) bl[nt].u = *(const uint4*)(Blo + off);
        }
        __syncthreads();
        *(uint4*)(sA_hi + 0) = a0;
        *(uint4*)(sA_hi + 8) = a1;
        if (TERMS == 3) {
            *(uint4*)(sA_lo + 0) = q0;
            *(uint4*)(sA_lo + 8) = q1;
        }
        __syncthreads();
#pragma unroll
        for (int mt = 0; mt < 4; mt++) {
            int me = (wm + mt * 16 + l16) * 40 + quad * 8;
            bf16x8 ah = *(const bf16x8*)&AsHi[me];
#pragma unroll
            for (int nt = 0; nt < 4; nt++)
                acc[mt][nt] = __builtin_amdgcn_mfma_f32_16x16x32_bf16(ah, bh[nt].v, acc[mt][nt], 0, 0, 0);
            if (TERMS == 3) {
                bf16x8 al = *(const bf16x8*)&AsLo[me];
#pragma unroll
                for (int nt = 0; nt < 4; nt++) {
                    acc[mt][nt] = __builtin_amdgcn_mfma_f32_16x16x32_bf16(ah, bl[nt].v, acc[mt][nt], 0, 0, 0);
                    acc[mt][nt] = __builtin_amdgcn_mfma_f32_16x16x32_bf16(al, bh[nt].v, acc[mt][nt], 0, 0, 0);
                }
            }
        }
    }

    float bv[4];
#pragma unroll
    for (int nt = 0; nt < 4; nt++) bv[nt] = bias[col0 + wn + nt * 16 + l16];
#pragma unroll
    for (int mt = 0; mt < 4; mt++) {
#pragma unroll
        for (int r = 0; r < 4; r++) {
            int m = row0 + wm + mt * 16 + quad * 4 + r;
            if (m < Nrows) {
#pragma unroll
                for (int nt = 0; nt < 4; nt++) {
                    int n = col0 + wn + nt * 16 + l16;
                    float vv = acc[mt][nt][r] + bv[nt];
                    if (OUT_BF16) ((u16*)Cv)[(size_t)m * M + n] = bf_hi(vv);
                    else          ((float*)Cv)[(size_t)m * M + n] = vv;
                }
            }
        }
    }
}

// ---------------- CSR build ----------------
__global__ void hist_kernel(const int* __restrict__ dst, int* __restrict__ counts) {
    int e = blockIdx.x * blockDim.x + threadIdx.x;
    if (e < N_EDGES) atomicAdd(&counts[dst[e]], 1);
}

__global__ __launch_bounds__(256) void scan_local_kernel(
    const int* __restrict__ counts, int* __restrict__ row_ptr, int* __restrict__ bsum) {
    __shared__ int buf[256];
    int b = blockIdx.x, tid = threadIdx.x;
    int i = b * 256 + tid;
    buf[tid] = (i < N_NODES) ? counts[i] : 0;
    __syncthreads();
    for (int off = 1; off < 256; off <<= 1) {
        int t = (tid >= off) ? buf[tid - off] : 0;
        __syncthreads();
        buf[tid] += t;
        __syncthreads();
    }
    if (i < N_NODES) row_ptr[i + 1] = buf[tid];
    if (tid == 255) bsum[b] = buf[255];
}

__global__ __launch_bounds__(256) void scan_fixup_kernel(
    const int* __restrict__ bsum, int* __restrict__ row_ptr) {
    __shared__ int red[256];
    int b = blockIdx.x, tid = threadIdx.x;
    red[tid] = (tid < b) ? bsum[tid] : 0;
    __syncthreads();
    for (int off = 128; off > 0; off >>= 1) {
        if (tid < off) red[tid] += red[tid + off];
        __syncthreads();
    }
    int offset = red[0];
    int i = b * 256 + tid;
    if (i < N_NODES) row_ptr[i + 1] += offset;
    if (b == 0 && tid == 0) row_ptr[0] = 0;
}

__global__ void scatter_kernel(const int* __restrict__ src, const int* __restrict__ dst,
                               const int* __restrict__ row_ptr,
                               int* __restrict__ cursor, int* __restrict__ csr_src) {
    int e = blockIdx.x * blockDim.x + threadIdx.x;
    if (e < N_EDGES) {
        int d = dst[e];
        int pos = atomicAdd(&cursor[d], 1);
        csr_src[row_ptr[d] + pos] = src[e];
    }
}

// -------- fused edge phase v3: one block per dst node -------------------
// Pass A: wave-per-edge score (lane owns 8 dims, halves = heads), exp in LDS.
// Pass B: wave-per-edge weighted accumulate (uint4 gathers, 8 acc/lane),
// cross-wave partial reduce, inv+ELU+skip RMW by wave 0.
__global__ __launch_bounds__(256) void edge_fused_kernel(
    const u16* __restrict__ FS16, const u16* __restrict__ FD16,
    const float* __restrict__ attn, const int* __restrict__ csr_src,
    const int* __restrict__ row_ptr, float* __restrict__ sexp,
    float* __restrict__ h1) {
    __shared__ int   src_s[ECAP];
    __shared__ float ex0[ECAP], ex1[ECAP];
    __shared__ float den[2];
    __shared__ float red[3 * 512];
    int n = blockIdx.x, tid = threadIdx.x;
    int lane = tid & 63, wave = tid >> 6;
    int beg = row_ptr[n], end = row_ptr[n + 1], deg = end - beg;
    bool small = deg <= ECAP;
    if (tid < 2) den[tid] = 0.f;

    float fdv[8], aw[8];
    {
        uint4 q = *(const uint4*)(FD16 + (size_t)n * 512 + 8 * lane);
        unpack2(q.x, fdv[0], fdv[1]); unpack2(q.y, fdv[2], fdv[3]);
        unpack2(q.z, fdv[4], fdv[5]); unpack2(q.w, fdv[6], fdv[7]);
        float4 a0 = *(const float4*)(attn + 8 * lane);
        float4 a1 = *(const float4*)(attn + 8 * lane + 4);
        aw[0] = a0.x; aw[1] = a0.y; aw[2] = a0.z; aw[3] = a0.w;
        aw[4] = a1.x; aw[5] = a1.y; aw[6] = a1.z; aw[7] = a1.w;
    }
    if (small) {
        for (int i = tid; i < deg; i += 256) src_s[i] = csr_src[beg + i];
    }
    __syncthreads();  // den init + src_s visible

    // ---- pass A: scores ----
    float dp = 0.f;  // lane0: head0 partial, lane32: head1 partial
    for (int j = wave; j < deg; j += 4) {
        int s = small ? src_s[j] : csr_src[beg + j];
        uint4 q = *(const uint4*)(FS16 + (size_t)s * 512 + 8 * lane);
        float f0, f1, p = 0.f;
        unpack2(q.x, f0, f1); p += lr(f0 + fdv[0]) * aw[0] + lr(f1 + fdv[1]) * aw[1];
        unpack2(q.y, f0, f1); p += lr(f0 + fdv[2]) * aw[2] + lr(f1 + fdv[3]) * aw[3];
        unpack2(q.z, f0, f1); p += lr(f0 + fdv[4]) * aw[4] + lr(f1 + fdv[5]) * aw[5];
        unpack2(q.w, f0, f1); p += lr(f0 + fdv[6]) * aw[6] + lr(f1 + fdv[7]) * aw[7];
#pragma unroll
        for (int off = 16; off > 0; off >>= 1) p += __shfl_xor(p, off, 64);
        float ex = expf(p);  // shift-invariant softmax: no max pass needed
        if (lane == 0)  { if (small) ex0[j] = ex; else sexp[2 * (beg + j)] = ex;     dp += ex; }
        if (lane == 32) { if (small) ex1[j] = ex; else sexp[2 * (beg + j) + 1] = ex; dp += ex; }
    }
    if (lane == 0)  atomicAdd(&den[0], dp);
    if (lane == 32) atomicAdd(&den[1], dp);
    __syncthreads();
    float inv = (lane < 32) ? (den[0] > 0.f ? 1.f / den[0] : 0.f)
                            : (den[1] > 0.f ? 1.f / den[1] : 0.f);

    // ---- pass B: weighted accumulation (8 dims / lane) ----
    float acc[8] = {0.f, 0.f, 0.f, 0.f, 0.f, 0.f, 0.f, 0.f};
    if (small) {
#pragma unroll 2
        for (int j = wave; j < deg; j += 4) {
            int s = src_s[j];
            float e = (lane < 32) ? ex0[j] : ex1[j];
            uint4 q = *(const uint4*)(FS16 + (size_t)s * 512 + 8 * lane);
            float f0, f1;
            unpack2(q.x, f0, f1); acc[0] += e * f0; acc[1] += e * f1;
            unpack2(q.y, f0, f1); acc[2] += e * f0; acc[3] += e * f1;
            unpack2(q.z, f0, f1); acc[4] += e * f0; acc[5] += e * f1;
            unpack2(q.w, f0, f1); acc[6] += e * f0; acc[7] += e * f1;
        }
    } else {
        for (int cbeg = 0; cbeg < deg; cbeg += ECAP) {
            int c = min(ECAP, deg - cbeg);
            for (int i = tid; i < c; i += 256) {
                int idx = beg + cbeg + i;
                src_s[i] = csr_src[idx];
                ex0[i] = sexp[2 * idx];
                ex1[i] = sexp[2 * idx + 1];
            }
            __syncthreads();
            for (int j = wave; j < c; j += 4) {
                int s = src_s[j];
                float e = (lane < 32) ? ex0[j] : ex1[j];
                uint4 q = *(const uint4*)(FS16 + (size_t)s * 512 + 8 * lane);
                float f0, f1;
                unpack2(q.x, f0, f1); acc[0] += e * f0; acc[1] += e * f1;
                unpack2(q.y, f0, f1); acc[2] += e * f0; acc[3] += e * f1;
                unpack2(q.z, f0, f1); acc[4] += e * f0; acc[5] += e * f1;
                unpack2(q.w, f0, f1); acc[6] += e * f0; acc[7] += e * f1;
            }
            __syncthreads();
        }
    }

    // ---- cross-wave reduce + inv + ELU + skip RMW ----
    if (wave > 0) {
        float* r = &red[(wave - 1) * 512 + lane * 8];
        *(float4*)(r + 0) = *(float4*)&acc[0];
        *(float4*)(r + 4) = *(float4*)&acc[4];
    }
    __syncthreads();
    if (wave == 0) {
#pragma unroll
        for (int w = 0; w < 3; w++) {
            const float* r = &red[w * 512 + lane * 8];
#pragma unroll
            for (int k = 0; k < 8; k++) acc[k] += r[k];
        }
        float* hp = h1 + (size_t)n * 512 + 8 * lane;
        float4 s0 = *(float4*)(hp);
        float4 s1 = *(float4*)(hp + 4);
        float v[8];
#pragma unroll
        for (int k = 0; k < 8; k++) {
            float x = acc[k] * inv;
            v[k] = x > 0.f ? x : expm1f(x);
        }
        s0.x += v[0]; s0.y += v[1]; s0.z += v[2]; s0.w += v[3];
        s1.x += v[4]; s1.y += v[5]; s1.z += v[6]; s1.w += v[7];
        *(float4*)(hp) = s0;
        *(float4*)(hp + 4) = s1;
    }
}

// ---------------- BatchNorm stats ----------------
__global__ __launch_bounds__(256) void bn_stats_kernel(const float* __restrict__ h1,
                                                       float* __restrict__ stats,
                                                       int rows_per_block) {
    int tid = threadIdx.x;
    int r0 = blockIdx.x * rows_per_block;
    int r1 = min(r0 + rows_per_block, N_NODES);
    float s0 = 0.f, q0 = 0.f, s1 = 0.f, q1 = 0.f;
    for (int r = r0; r < r1; r++) {
        float a = h1[(size_t)r * F2 + tid];
        float b = h1[(size_t)r * F2 + 256 + tid];
        s0 += a; q0 += a * a;
        s1 += b; q1 += b * b;
    }
    atomicAdd(&stats[tid], s0);
    atomicAdd(&stats[256 + tid], s1);
    atomicAdd(&stats[512 + tid], q0);
    atomicAdd(&stats[512 + 256 + tid], q1);
}

__global__ void bn_finalize_kernel(const float* __restrict__ stats,
                                   const float* __restrict__ gamma,
                                   const float* __restrict__ beta,
                                   float* __restrict__ bscale, float* __restrict__ bshift) {
    int c = threadIdx.x;  // 512 threads
    float mu = stats[c] / (float)N_NODES;
    float var = stats[512 + c] / (float)N_NODES - mu * mu;
    float sc = gamma[c] * rsqrtf(var + EPS_BN);
    bscale[c] = sc;
    bshift[c] = beta[c] - mu * sc;
}

// ---------------- gate scores (b_gate dropped: softmax shift-invariant) -
__global__ __launch_bounds__(256) void gate_kernel(const float* __restrict__ hr,
                                                   const float* __restrict__ wg,
                                                   float* __restrict__ gate) {
    int n = blockIdx.x * 4 + (threadIdx.x >> 6);
    int lane = threadIdx.x & 63;
    const float4* row = (const float4*)(hr + (size_t)n * HID);
    const float4* w = (const float4*)wg;
    float4 a = row[lane], b = w[lane];
    float p = a.x * b.x + a.y * b.y + a.z * b.z + a.w * b.w;
#pragma unroll
    for (int off = 32; off > 0; off >>= 1) p += __shfl_down(p, off, 64);
    if (lane == 0) gate[n] = p;
}

// ---------------- per-graph attention pooling: 8 partial blocks / graph -
__device__ __forceinline__ int lower_bound_dev(const int* a, int n, int v) {
    int lo = 0, hi = n;
    while (lo < hi) {
        int mid = (lo + hi) >> 1;
        if (a[mid] < v) lo = mid + 1; else hi = mid;
    }
    return lo;
}

__global__ __launch_bounds__(256) void pool_partial_kernel(
    const float* __restrict__ hr, const float* __restrict__ gate,
    const int* __restrict__ gids, float* __restrict__ h_gnum,
    float* __restrict__ gden) {
    int b = blockIdx.x;
    int g = b >> 3, part = b & 7;
    int tid = threadIdx.x;
    int start = lower_bound_dev(gids, N_NODES, g);
    int end = lower_bound_dev(gids, N_NODES, g + 1);
    int span = end - start;
    int p_beg = start + (span * part) / 8;
    int p_end = start + (span * (part + 1)) / 8;
    if (p_beg >= p_end) return;
    __shared__ float wa[256];
    __shared__ float red[256];
    float acc = 0.f, denacc = 0.f;
    for (int cbeg = p_beg; cbeg < p_end; cbeg += 256) {
        int c = min(256, p_end - cbeg);
        float e = 0.f;
        if (tid < c) { e = expf(gate[cbeg + tid]); wa[tid] = e; }  // |gate| << 1: safe
        red[tid] = (tid < c) ? e : 0.f;
        __syncthreads();
        for (int off = 128; off > 0; off >>= 1) {
            if (tid < off) red[tid] += red[tid + off];
            __syncthreads();
        }
        denacc += red[0];
        for (int i = 0; i < c; i++) acc += wa[i] * hr[(size_t)(cbeg + i) * HID + tid];
        __syncthreads();
    }
    atomicAdd(&h_gnum[g * HID + tid], acc);
    if (tid == 0) atomicAdd(&gden[g], denacc);
}

// ---------------- classifier (finalizes pooling divide) -----------------
__global__ __launch_bounds__(128) void classifier_kernel(
    const float* __restrict__ h_gnum, const float* __restrict__ gden,
    const float* __restrict__ W1, const float* __restrict__ b1,
    const float* __restrict__ W2, const float* __restrict__ b2,
    float* __restrict__ out) {
    int g = blockIdx.x;
    int tid = threadIdx.x;  // 128
    __shared__ float hg[256];
    __shared__ float z1[128];
    float d = gden[g];
    float invd = d > 0.f ? 1.f / d : 0.f;
    hg[tid] = h_gnum[g * HID + tid] * invd;
    hg[tid + 128] = h_gnum[g * HID + tid + 128] * invd;
    __syncthreads();
    float a = b1[tid];
#pragma unroll 8
    for (int k = 0; k < 256; k++) a += hg[k] * W1[k * 128 + tid];
    z1[tid] = a > 0.f ? a : 0.f;
    __syncthreads();
    if (tid < 10) {
        float o = b2[tid];
#pragma unroll 8
        for (int j = 0; j < 128; j++) o += z1[j] * W2[j * 10 + tid];
        out[g * 10 + tid] = o;
    }
}

// ---------------- launcher ----------------
extern "C" void kernel_launch(void* const* d_in, const int* in_sizes, int n_in,
                              void* d_out, int out_size, void* d_ws, size_t ws_size,
                              hipStream_t stream) {
    const float* feat   = (const float*)d_in[0];
    const int*   src    = (const int*)d_in[1];
    const int*   dst    = (const int*)d_in[2];
    const int*   gids   = (const int*)d_in[3];
    const float* W_src  = (const float*)d_in[4];
    const float* b_src  = (const float*)d_in[5];
    const float* W_dst  = (const float*)d_in[6];
    const float* b_dst  = (const float*)d_in[7];
    const float* attn   = (const float*)d_in[8];
    const float* W_skip = (const float*)d_in[9];
    const float* b_skip = (const float*)d_in[10];
    const float* gamma  = (const float*)d_in[11];
    const float* beta   = (const float*)d_in[12];
    const float* W_red  = (const float*)d_in[13];
    const float* b_red  = (const float*)d_in[14];
    const float* w_gate = (const float*)d_in[15];
    const float* W1     = (const float*)d_in[17];
    const float* b1     = (const float*)d_in[18];
    const float* W2     = (const float*)d_in[19];
    const float* b2     = (const float*)d_in[20];
    float* out = (float*)d_out;

    char* p = (char*)d_ws;
    auto alloc = [&](size_t bytes) -> char* {
        char* r = p;
        p += (bytes + 255) & ~(size_t)255;
        return r;
    };
    u16*   FS16     = (u16*)alloc((size_t)N_NODES * F2 * 2);
    u16*   FD16     = (u16*)alloc((size_t)N_NODES * F2 * 2);
    float* h1       = (float*)alloc((size_t)N_NODES * F2 * 4);
    float* sexp     = (float*)alloc((size_t)N_EDGES * 2 * 4);  // fallback only
    float* gate     = (float*)alloc((size_t)N_NODES * 4);
    float* stats    = (float*)alloc(1024 * 4);
    float* bn_scale = (float*)alloc(512 * 4);
    float* bn_shift = (float*)alloc(512 * 4);
    float* h_gnum   = (float*)alloc((size_t)N_GRAPH * HID * 4);
    float* gden     = (float*)alloc((size_t)N_GRAPH * 4);
    int* counts     = (int*)alloc((size_t)N_NODES * 4);
    int* row_ptr    = (int*)alloc((size_t)(N_NODES + 1) * 4);
    int* cursor     = (int*)alloc((size_t)N_NODES * 4);
    int* csr_src    = (int*)alloc((size_t)N_EDGES * 4);
    int* bsum       = (int*)alloc((size_t)SCAN_BLOCKS * 4);
    u16* Fhi        = (u16*)alloc((size_t)N_NODES * IN_DIM * 2);  // aliased as hr later
    u16* Wthi       = (u16*)alloc((size_t)4 * 512 * 512 * 2);
    u16* Wtlo       = (u16*)alloc((size_t)4 * 512 * 512 * 2);
    // hr (20.48 MB) aliases Fhi (20.48 MB): Fhi's last use (input GEMMs)
    // strictly precedes hr's first write (reducer GEMM).
    float* hr = (float*)Fhi;
    (void)ws_size; (void)in_sizes; (void)n_in; (void)out_size;

    const size_t WSZ = (size_t)512 * 512;

    // 1. init + input conversions
    init_zero_kernel<<<(N_NODES + 255) / 256, 256, 0, stream>>>(counts, cursor, stats, h_gnum, gden);
    split_feat_kernel<<<(N_NODES * IN_DIM / 8 + 255) / 256, 256, 0, stream>>>(
        feat, Fhi, N_NODES * IN_DIM / 8);
    split_wt_kernel<<<dim3(16, 16, 4), dim3(32, 8), 0, stream>>>(
        W_src, W_dst, W_skip, W_red, Wthi, Wtlo);

    // 2. input GEMMs: all 1-term bf16 (error evidence: invisible at output)
    dim3 g512((N_NODES + 127) / 128, 4);
    gemm_mfma<1, true, false><<<g512, 256, 0, stream>>>(
        Fhi, nullptr, Wthi + 0 * WSZ, nullptr, b_src, FS16, N_NODES, F2, nullptr, nullptr);
    gemm_mfma<1, true, false><<<g512, 256, 0, stream>>>(
        Fhi, nullptr, Wthi + 1 * WSZ, nullptr, b_dst, FD16, N_NODES, F2, nullptr, nullptr);
    gemm_mfma<1, false, false><<<g512, 256, 0, stream>>>(
        Fhi, nullptr, Wthi + 2 * WSZ, nullptr, b_skip, h1, N_NODES, F2, nullptr, nullptr);

    // 3-5. CSR by dst
    hist_kernel<<<(N_EDGES + 255) / 256, 256, 0, stream>>>(dst, counts);
    scan_local_kernel<<<SCAN_BLOCKS, 256, 0, stream>>>(counts, row_ptr, bsum);
    scan_fixup_kernel<<<SCAN_BLOCKS, 256, 0, stream>>>(bsum, row_ptr);
    scatter_kernel<<<(N_EDGES + 255) / 256, 256, 0, stream>>>(src, dst, row_ptr, cursor, csr_src);

    // 6. fused edge phase v3
    edge_fused_kernel<<<N_NODES, 256, 0, stream>>>(FS16, FD16, attn, csr_src, row_ptr, sexp, h1);

    // 7-8. BatchNorm stats -> scale/shift
    bn_stats_kernel<<<500, 256, 0, stream>>>(h1, stats, 40);
    bn_finalize_kernel<<<1, 512, 0, stream>>>(stats, gamma, beta, bn_scale, bn_shift);

    // 9. hr = BN(h1) @ W_red + b_red  (MFMA, 3-term, BN fold at staging)
    dim3 g256((N_NODES + 127) / 128, 2);
    gemm_mfma<3, false, true><<<g256, 256, 0, stream>>>(
        nullptr, h1, Wthi + 3 * WSZ, Wtlo + 3 * WSZ, b_red, hr, N_NODES, HID,
        bn_scale, bn_shift);

    // 10. gate
    gate_kernel<<<N_NODES / 4, 256, 0, stream>>>(hr, w_gate, gate);

    // 11. per-graph pooling (8 partial blocks per graph)
    pool_partial_kernel<<<N_GRAPH * 8, 256, 0, stream>>>(hr, gate, gids, h_gnum, gden);

    // 12. classifier (+ pooling divide)
    classifier_kernel<<<N_GRAPH, 128, 0, stream>>>(h_gnum, gden, W1, b1, W2, b2, out);
}

// Round 7
// 425.812 us; speedup vs baseline: 2.9978x; 1.0746x over previous
//
#include <hip/hip_runtime.h>
#include <math.h>

#define N_NODES 20000
#define N_EDGES 320000
#define N_GRAPH 64
#define IN_DIM  512
#define HID     256
#define F2      512   // HEADS*HID
#define EPS_BN  1e-5f
#define SLOPE   0.2f
#define SCAN_BLOCKS 79   // ceil(20000/256)

typedef unsigned short u16;
typedef __attribute__((ext_vector_type(8))) short bf16x8;
typedef __attribute__((ext_vector_type(4))) float floatx4;

// bf16 helpers: storage = upper 16 bits of fp32, round-to-nearest-even
__device__ __forceinline__ u16 bf_hi(float x) {
    unsigned int u = __float_as_uint(x);
    return (u16)((u + 0x7fffu + ((u >> 16) & 1u)) >> 16);
}
__device__ __forceinline__ float bf_val(u16 h) {
    return __uint_as_float((unsigned int)h << 16);
}
__device__ __forceinline__ void unpack2(unsigned int u, float& lo, float& hi) {
    lo = __uint_as_float(u << 16);
    hi = __uint_as_float(u & 0xffff0000u);
}
__device__ __forceinline__ float lr(float x) { return fmaxf(x, SLOPE * x); }

// ---------------- init: zero the ws regions that need it ----------------
__global__ void init_zero_kernel(int* counts, int* cursor, float* stats,
                                 float* h_gnum, float* gden) {
    int i = blockIdx.x * blockDim.x + threadIdx.x;
    if (i < N_NODES) { counts[i] = 0; cursor[i] = 0; }
    if (i < 1024) stats[i] = 0.f;
    if (i < N_GRAPH * HID) h_gnum[i] = 0.f;
    if (i < N_GRAPH) gden[i] = 0.f;
}

// ---------------- feat -> bf16 (row-major preserved) --------------------
__global__ __launch_bounds__(256) void split_feat_kernel(
    const float* __restrict__ X, u16* __restrict__ Hi, int total8) {
    int i = blockIdx.x * 256 + threadIdx.x;
    if (i >= total8) return;
    size_t base = (size_t)i * 8;
    float4 x0 = *(const float4*)(X + base);
    float4 x1 = *(const float4*)(X + base + 4);
    float xs[8] = {x0.x, x0.y, x0.z, x0.w, x1.x, x1.y, x1.z, x1.w};
    union { u16 s[8]; uint4 v; } h;
#pragma unroll
    for (int j = 0; j < 8; j++) h.s[j] = bf_hi(xs[j]);
    *(uint4*)(Hi + base) = h.v;
}

// --- transpose + split 4 weights: W[k][n] -> Wt[n][k] hi/lo -------------
// z=0..2: 512x512 (W_src,W_dst,W_skip); z=3: W_red 512x256.
__global__ __launch_bounds__(256) void split_wt_kernel(
    const float* __restrict__ Ws, const float* __restrict__ Wd,
    const float* __restrict__ Wk, const float* __restrict__ Wr,
    u16* __restrict__ Hi, u16* __restrict__ Lo) {
    __shared__ float t[32][33];
    int w = blockIdx.z;
    int ncols = (w == 3) ? 256 : 512;
    int n0 = blockIdx.y * 32;
    if (n0 >= ncols) return;
    const float* W = (w == 0) ? Ws : ((w == 1) ? Wd : ((w == 2) ? Wk : Wr));
    size_t obase = (size_t)w * 512 * 512;
    int k0 = blockIdx.x * 32;
    int tx = threadIdx.x, ty = threadIdx.y;  // 32 x 8
#pragma unroll
    for (int i = 0; i < 4; i++)
        t[ty * 4 + i][tx] = W[(size_t)(k0 + ty * 4 + i) * ncols + n0 + tx];
    __syncthreads();
#pragma unroll
    for (int i = 0; i < 4; i++) {
        float x = t[tx][ty * 4 + i];  // = W[k0+tx][n0+ty*4+i]
        u16 hh = bf_hi(x);
        size_t o = obase + (size_t)(n0 + ty * 4 + i) * 512 + k0 + tx;
        Hi[o] = hh;
        Lo[o] = bf_hi(x - bf_val(hh));
    }
}

// ------- fused triple MFMA GEMM: {fs,fd,skip} = feat @ {Ws,Wd,Wk} -------
// 1-term bf16 (output rounding dominates). grid.y in [0,12): w = y>>2,
// col-tile = y&3. Single launch: one dispatch tail instead of three.
__global__ __launch_bounds__(256) void gemm_mfma_triple(
    const u16* __restrict__ Fhi, const u16* __restrict__ Wthi,
    const float* __restrict__ b_src, const float* __restrict__ b_dst,
    const float* __restrict__ b_skip,
    u16* __restrict__ FS16, u16* __restrict__ FD16, float* __restrict__ h1) {
    __shared__ u16 AsHi[128 * 40];
    int tid = threadIdx.x;
    int w_idx = blockIdx.y >> 2;
    int col0 = (blockIdx.y & 3) * 128;
    int row0 = blockIdx.x * 128;
    int lane = tid & 63, wave = tid >> 6;
    int wm = (wave & 1) * 64, wn = (wave >> 1) * 64;
    int quad = lane >> 4, l16 = lane & 15;

    int sr = tid >> 1, sh = (tid & 1) * 16;
    int grow = row0 + sr;
    bool ok = grow < N_NODES;
    u16* sA = &AsHi[sr * 40 + sh];
    const u16* Wb = Wthi + (size_t)w_idx * 512 * 512;

    floatx4 acc[4][4];
#pragma unroll
    for (int i = 0; i < 4; i++)
#pragma unroll
        for (int j = 0; j < 4; j++) acc[i][j] = (floatx4){0.f, 0.f, 0.f, 0.f};

    for (int k0 = 0; k0 < 512; k0 += 32) {
        uint4 a0 = make_uint4(0, 0, 0, 0), a1 = a0;
        if (ok) {
            const u16* g = Fhi + (size_t)grow * 512 + k0 + sh;
            a0 = *(const uint4*)(g);
            a1 = *(const uint4*)(g + 8);
        }
        union { uint4 u; bf16x8 v; } bh[4];
#pragma unroll
        for (int nt = 0; nt < 4; nt++) {
            size_t off = (size_t)(col0 + wn + nt * 16 + l16) * 512 + k0 + quad * 8;
            bh[nt].u = *(const uint4*)(Wb + off);
        }
        __syncthreads();
        *(uint4*)(sA + 0) = a0;
        *(uint4*)(sA + 8) = a1;
        __syncthreads();
#pragma unroll
        for (int mt = 0; mt < 4; mt++) {
            int me = (wm + mt * 16 + l16) * 40 + quad * 8;
            bf16x8 ah = *(const bf16x8*)&AsHi[me];
#pragma unroll
            for (int nt = 0; nt < 4; nt++)
                acc[mt][nt] = __builtin_amdgcn_mfma_f32_16x16x32_bf16(ah, bh[nt].v, acc[mt][nt], 0, 0, 0);
        }
    }

    const float* bias = (w_idx == 0) ? b_src : ((w_idx == 1) ? b_dst : b_skip);
    float bv[4];
#pragma unroll
    for (int nt = 0; nt < 4; nt++) bv[nt] = bias[col0 + wn + nt * 16 + l16];
#pragma unroll
    for (int mt = 0; mt < 4; mt++) {
#pragma unroll
        for (int r = 0; r < 4; r++) {
            int m = row0 + wm + mt * 16 + quad * 4 + r;
            if (m < N_NODES) {
#pragma unroll
                for (int nt = 0; nt < 4; nt++) {
                    int n = col0 + wn + nt * 16 + l16;
                    float vv = acc[mt][nt][r] + bv[nt];
                    if (w_idx == 0)      FS16[(size_t)m * 512 + n] = bf_hi(vv);
                    else if (w_idx == 1) FD16[(size_t)m * 512 + n] = bf_hi(vv);
                    else                 h1[(size_t)m * 512 + n] = vv;
                }
            }
        }
    }
}

// ------------------- MFMA GEMM (reducer): 3-term + BN fold --------------
__global__ __launch_bounds__(256) void gemm_mfma_red(
    const float* __restrict__ Af,
    const u16* __restrict__ Bhi, const u16* __restrict__ Blo,
    const float* __restrict__ bias, float* __restrict__ C,
    int Nrows, int M,
    const float* __restrict__ bscale, const float* __restrict__ bshift) {
    __shared__ u16 AsHi[128 * 40];
    __shared__ u16 AsLo[128 * 40];
    __shared__ float sBN[1024];
    int tid = threadIdx.x;
    int row0 = blockIdx.x * 128;
    int col0 = blockIdx.y * 128;
    int lane = tid & 63, wave = tid >> 6;
    int wm = (wave & 1) * 64, wn = (wave >> 1) * 64;
    int quad = lane >> 4, l16 = lane & 15;

    sBN[tid] = bscale[tid]; sBN[256 + tid] = bscale[256 + tid];
    sBN[512 + tid] = bshift[tid]; sBN[768 + tid] = bshift[256 + tid];
    __syncthreads();

    int sr = tid >> 1, sh = (tid & 1) * 16;
    int grow = row0 + sr;
    bool ok = grow < Nrows;
    u16* sA_hi = &AsHi[sr * 40 + sh];
    u16* sA_lo = &AsLo[sr * 40 + sh];

    floatx4 acc[4][4];
#pragma unroll
    for (int i = 0; i < 4; i++)
#pragma unroll
        for (int j = 0; j < 4; j++) acc[i][j] = (floatx4){0.f, 0.f, 0.f, 0.f};

    for (int k0 = 0; k0 < 512; k0 += 32) {
        float v[16];
        if (ok) {
            const float* g = Af + (size_t)grow * 512 + k0 + sh;
            *(float4*)&v[0]  = *(const float4*)(g);
            *(float4*)&v[4]  = *(const float4*)(g + 4);
            *(float4*)&v[8]  = *(const float4*)(g + 8);
            *(float4*)&v[12] = *(const float4*)(g + 12);
        } else {
#pragma unroll
            for (int j = 0; j < 16; j++) v[j] = 0.f;
        }
        union { u16 s[8]; uint4 u; } h0_, h1_, l0_, l1_;
#pragma unroll
        for (int j = 0; j < 16; j++) {
            int kc = k0 + sh + j;
            float x = v[j] * sBN[kc] + sBN[512 + kc];
            u16 hh = bf_hi(x);
            u16 ll = bf_hi(x - bf_val(hh));
            if (j < 8) { h0_.s[j] = hh; l0_.s[j] = ll; }
            else       { h1_.s[j - 8] = hh; l1_.s[j - 8] = ll; }
        }
        union { uint4 u; bf16x8 v; } bh[4], bl[4];
#pragma unroll
        for (int nt = 0; nt < 4; nt++) {
            size_t off = (size_t)(col0 + wn + nt * 16 + l16) * 512 + k0 + quad * 8;
            bh[nt].u = *(const uint4*)(Bhi + off);
            bl[nt].u = *(const uint4*)(Blo + off);
        }
        __syncthreads();
        *(uint4*)(sA_hi + 0) = h0_.u;
        *(uint4*)(sA_hi + 8) = h1_.u;
        *(uint4*)(sA_lo + 0) = l0_.u;
        *(uint4*)(sA_lo + 8) = l1_.u;
        __syncthreads();
#pragma unroll
        for (int mt = 0; mt < 4; mt++) {
            int me = (wm + mt * 16 + l16) * 40 + quad * 8;
            bf16x8 ah = *(const bf16x8*)&AsHi[me];
            bf16x8 al = *(const bf16x8*)&AsLo[me];
#pragma unroll
            for (int nt = 0; nt < 4; nt++) {
                acc[mt][nt] = __builtin_amdgcn_mfma_f32_16x16x32_bf16(ah, bh[nt].v, acc[mt][nt], 0, 0, 0);
                acc[mt][nt] = __builtin_amdgcn_mfma_f32_16x16x32_bf16(ah, bl[nt].v, acc[mt][nt], 0, 0, 0);
                acc[mt][nt] = __builtin_amdgcn_mfma_f32_16x16x32_bf16(al, bh[nt].v, acc[mt][nt], 0, 0, 0);
            }
        }
    }

    float bv[4];
#pragma unroll
    for (int nt = 0; nt < 4; nt++) bv[nt] = bias[col0 + wn + nt * 16 + l16];
#pragma unroll
    for (int mt = 0; mt < 4; mt++) {
#pragma unroll
        for (int r = 0; r < 4; r++) {
            int m = row0 + wm + mt * 16 + quad * 4 + r;
            if (m < Nrows) {
#pragma unroll
                for (int nt = 0; nt < 4; nt++) {
                    int n = col0 + wn + nt * 16 + l16;
                    C[(size_t)m * M + n] = acc[mt][nt][r] + bv[nt];
                }
            }
        }
    }
}

// ---------------- CSR build ----------------
__global__ void hist_kernel(const int* __restrict__ dst, int* __restrict__ counts) {
    int e = blockIdx.x * blockDim.x + threadIdx.x;
    if (e < N_EDGES) atomicAdd(&counts[dst[e]], 1);
}

__global__ __launch_bounds__(256) void scan_local_kernel(
    const int* __restrict__ counts, int* __restrict__ row_ptr, int* __restrict__ bsum) {
    __shared__ int buf[256];
    int b = blockIdx.x, tid = threadIdx.x;
    int i = b * 256 + tid;
    buf[tid] = (i < N_NODES) ? counts[i] : 0;
    __syncthreads();
    for (int off = 1; off < 256; off <<= 1) {
        int t = (tid >= off) ? buf[tid - off] : 0;
        __syncthreads();
        buf[tid] += t;
        __syncthreads();
    }
    if (i < N_NODES) row_ptr[i + 1] = buf[tid];
    if (tid == 255) bsum[b] = buf[255];
}

__global__ __launch_bounds__(256) void scan_fixup_kernel(
    const int* __restrict__ bsum, int* __restrict__ row_ptr) {
    __shared__ int red[256];
    int b = blockIdx.x, tid = threadIdx.x;
    red[tid] = (tid < b) ? bsum[tid] : 0;
    __syncthreads();
    for (int off = 128; off > 0; off >>= 1) {
        if (tid < off) red[tid] += red[tid + off];
        __syncthreads();
    }
    int offset = red[0];
    int i = b * 256 + tid;
    if (i < N_NODES) row_ptr[i + 1] += offset;
    if (b == 0 && tid == 0) row_ptr[0] = 0;
}

__global__ void scatter_kernel(const int* __restrict__ src, const int* __restrict__ dst,
                               const int* __restrict__ row_ptr,
                               int* __restrict__ cursor, int* __restrict__ csr_src) {
    int e = blockIdx.x * blockDim.x + threadIdx.x;
    if (e < N_EDGES) {
        int d = dst[e];
        int pos = atomicAdd(&cursor[d], 1);
        csr_src[row_ptr[d] + pos] = src[e];
    }
}

// -------- fused edge phase v4: SINGLE PASS ------------------------------
// Streaming shift-invariant softmax: per edge, load FS row once, score ->
// exp (butterfly gives it to every lane) -> immediately accumulate
// numerator (values still in registers) and denominator; normalize in the
// epilogue. No second gather, no exp staging, no sexp buffer.
__global__ __launch_bounds__(256) void edge_fused_kernel(
    const u16* __restrict__ FS16, const u16* __restrict__ FD16,
    const float* __restrict__ attn, const int* __restrict__ csr_src,
    const int* __restrict__ row_ptr, float* __restrict__ h1) {
    __shared__ float red[3 * 512];
    __shared__ float den[2];
    int n = blockIdx.x, tid = threadIdx.x;
    int lane = tid & 63, wave = tid >> 6;
    int beg = row_ptr[n], end = row_ptr[n + 1], deg = end - beg;
    if (tid < 2) den[tid] = 0.f;

    float fdv[8], aw[8];
    {
        uint4 q = *(const uint4*)(FD16 + (size_t)n * 512 + 8 * lane);
        unpack2(q.x, fdv[0], fdv[1]); unpack2(q.y, fdv[2], fdv[3]);
        unpack2(q.z, fdv[4], fdv[5]); unpack2(q.w, fdv[6], fdv[7]);
        float4 a0 = *(const float4*)(attn + 8 * lane);
        float4 a1 = *(const float4*)(attn + 8 * lane + 4);
        aw[0] = a0.x; aw[1] = a0.y; aw[2] = a0.z; aw[3] = a0.w;
        aw[4] = a1.x; aw[5] = a1.y; aw[6] = a1.z; aw[7] = a1.w;
    }
    __syncthreads();  // den init visible before LDS atomics

    float acc[8] = {0.f, 0.f, 0.f, 0.f, 0.f, 0.f, 0.f, 0.f};
    float dp = 0.f;
    for (int j = wave; j < deg; j += 4) {
        int s = csr_src[beg + j];
        uint4 q = *(const uint4*)(FS16 + (size_t)s * 512 + 8 * lane);
        float f[8];
        unpack2(q.x, f[0], f[1]); unpack2(q.y, f[2], f[3]);
        unpack2(q.z, f[4], f[5]); unpack2(q.w, f[6], f[7]);
        float p = 0.f;
#pragma unroll
        for (int k = 0; k < 8; k++) p += lr(f[k] + fdv[k]) * aw[k];
        // butterfly over the 32-lane half: every lane gets its head's score
#pragma unroll
        for (int off = 16; off > 0; off >>= 1) p += __shfl_xor(p, off, 64);
        float ex = expf(p);  // shift-invariant: no max pass needed
#pragma unroll
        for (int k = 0; k < 8; k++) acc[k] += ex * f[k];
        if ((lane & 31) == 0) dp += ex;
    }
    if ((lane & 31) == 0) atomicAdd(&den[lane >> 5], dp);

    // cross-wave reduce + normalize + ELU + skip RMW
    if (wave > 0) {
        float* r = &red[(wave - 1) * 512 + lane * 8];
        *(float4*)(r + 0) = *(float4*)&acc[0];
        *(float4*)(r + 4) = *(float4*)&acc[4];
    }
    __syncthreads();
    if (wave == 0) {
#pragma unroll
        for (int w = 0; w < 3; w++) {
            const float* r = &red[w * 512 + lane * 8];
#pragma unroll
            for (int k = 0; k < 8; k++) acc[k] += r[k];
        }
        float d = (lane < 32) ? den[0] : den[1];
        float inv = d > 0.f ? 1.f / d : 0.f;
        float* hp = h1 + (size_t)n * 512 + 8 * lane;
        float4 s0 = *(float4*)(hp);
        float4 s1 = *(float4*)(hp + 4);
        float v[8];
#pragma unroll
        for (int k = 0; k < 8; k++) {
            float x = acc[k] * inv;
            v[k] = x > 0.f ? x : expm1f(x);
        }
        s0.x += v[0]; s0.y += v[1]; s0.z += v[2]; s0.w += v[3];
        s1.x += v[4]; s1.y += v[5]; s1.z += v[6]; s1.w += v[7];
        *(float4*)(hp) = s0;
        *(float4*)(hp + 4) = s1;
    }
}

// ---------------- BatchNorm stats ----------------
__global__ __launch_bounds__(256) void bn_stats_kernel(const float* __restrict__ h1,
                                                       float* __restrict__ stats,
                                                       int rows_per_block) {
    int tid = threadIdx.x;
    int r0 = blockIdx.x * rows_per_block;
    int r1 = min(r0 + rows_per_block, N_NODES);
    float s0 = 0.f, q0 = 0.f, s1 = 0.f, q1 = 0.f;
    for (int r = r0; r < r1; r++) {
        float a = h1[(size_t)r * F2 + tid];
        float b = h1[(size_t)r * F2 + 256 + tid];
        s0 += a; q0 += a * a;
        s1 += b; q1 += b * b;
    }
    atomicAdd(&stats[tid], s0);
    atomicAdd(&stats[256 + tid], s1);
    atomicAdd(&stats[512 + tid], q0);
    atomicAdd(&stats[512 + 256 + tid], q1);
}

__global__ void bn_finalize_kernel(const float* __restrict__ stats,
                                   const float* __restrict__ gamma,
                                   const float* __restrict__ beta,
                                   float* __restrict__ bscale, float* __restrict__ bshift) {
    int c = threadIdx.x;  // 512 threads
    float mu = stats[c] / (float)N_NODES;
    float var = stats[512 + c] / (float)N_NODES - mu * mu;
    float sc = gamma[c] * rsqrtf(var + EPS_BN);
    bscale[c] = sc;
    bshift[c] = beta[c] - mu * sc;
}

// ---------------- gate scores (b_gate dropped: softmax shift-invariant) -
__global__ __launch_bounds__(256) void gate_kernel(const float* __restrict__ hr,
                                                   const float* __restrict__ wg,
                                                   float* __restrict__ gate) {
    int n = blockIdx.x * 4 + (threadIdx.x >> 6);
    int lane = threadIdx.x & 63;
    const float4* row = (const float4*)(hr + (size_t)n * HID);
    const float4* w = (const float4*)wg;
    float4 a = row[lane], b = w[lane];
    float p = a.x * b.x + a.y * b.y + a.z * b.z + a.w * b.w;
#pragma unroll
    for (int off = 32; off > 0; off >>= 1) p += __shfl_down(p, off, 64);
    if (lane == 0) gate[n] = p;
}

// ---------------- per-graph attention pooling: 8 partial blocks / graph -
__device__ __forceinline__ int lower_bound_dev(const int* a, int n, int v) {
    int lo = 0, hi = n;
    while (lo < hi) {
        int mid = (lo + hi) >> 1;
        if (a[mid] < v) lo = mid + 1; else hi = mid;
    }
    return lo;
}

__global__ __launch_bounds__(256) void pool_partial_kernel(
    const float* __restrict__ hr, const float* __restrict__ gate,
    const int* __restrict__ gids, float* __restrict__ h_gnum,
    float* __restrict__ gden) {
    int b = blockIdx.x;
    int g = b >> 3, part = b & 7;
    int tid = threadIdx.x;
    int start = lower_bound_dev(gids, N_NODES, g);
    int end = lower_bound_dev(gids, N_NODES, g + 1);
    int span = end - start;
    int p_beg = start + (span * part) / 8;
    int p_end = start + (span * (part + 1)) / 8;
    if (p_beg >= p_end) return;
    __shared__ float wa[256];
    __shared__ float red[256];
    float acc = 0.f, denacc = 0.f;
    for (int cbeg = p_beg; cbeg < p_end; cbeg += 256) {
        int c = min(256, p_end - cbeg);
        float e = 0.f;
        if (tid < c) { e = expf(gate[cbeg + tid]); wa[tid] = e; }  // |gate| << 1: safe
        red[tid] = (tid < c) ? e : 0.f;
        __syncthreads();
        for (int off = 128; off > 0; off >>= 1) {
            if (tid < off) red[tid] += red[tid + off];
            __syncthreads();
        }
        denacc += red[0];
        for (int i = 0; i < c; i++) acc += wa[i] * hr[(size_t)(cbeg + i) * HID + tid];
        __syncthreads();
    }
    atomicAdd(&h_gnum[g * HID + tid], acc);
    if (tid == 0) atomicAdd(&gden[g], denacc);
}

// ---------------- classifier (finalizes pooling divide) -----------------
__global__ __launch_bounds__(128) void classifier_kernel(
    const float* __restrict__ h_gnum, const float* __restrict__ gden,
    const float* __restrict__ W1, const float* __restrict__ b1,
    const float* __restrict__ W2, const float* __restrict__ b2,
    float* __restrict__ out) {
    int g = blockIdx.x;
    int tid = threadIdx.x;  // 128
    __shared__ float hg[256];
    __shared__ float z1[128];
    float d = gden[g];
    float invd = d > 0.f ? 1.f / d : 0.f;
    hg[tid] = h_gnum[g * HID + tid] * invd;
    hg[tid + 128] = h_gnum[g * HID + tid + 128] * invd;
    __syncthreads();
    float a = b1[tid];
#pragma unroll 8
    for (int k = 0; k < 256; k++) a += hg[k] * W1[k * 128 + tid];
    z1[tid] = a > 0.f ? a : 0.f;
    __syncthreads();
    if (tid < 10) {
        float o = b2[tid];
#pragma unroll 8
        for (int j = 0; j < 128; j++) o += z1[j] * W2[j * 10 + tid];
        out[g * 10 + tid] = o;
    }
}

// ---------------- launcher ----------------
extern "C" void kernel_launch(void* const* d_in, const int* in_sizes, int n_in,
                              void* d_out, int out_size, void* d_ws, size_t ws_size,
                              hipStream_t stream) {
    const float* feat   = (const float*)d_in[0];
    const int*   src    = (const int*)d_in[1];
    const int*   dst    = (const int*)d_in[2];
    const int*   gids   = (const int*)d_in[3];
    const float* W_src  = (const float*)d_in[4];
    const float* b_src  = (const float*)d_in[5];
    const float* W_dst  = (const float*)d_in[6];
    const float* b_dst  = (const float*)d_in[7];
    const float* attn   = (const float*)d_in[8];
    const float* W_skip = (const float*)d_in[9];
    const float* b_skip = (const float*)d_in[10];
    const float* gamma  = (const float*)d_in[11];
    const float* beta   = (const float*)d_in[12];
    const float* W_red  = (const float*)d_in[13];
    const float* b_red  = (const float*)d_in[14];
    const float* w_gate = (const float*)d_in[15];
    const float* W1     = (const float*)d_in[17];
    const float* b1     = (const float*)d_in[18];
    const float* W2     = (const float*)d_in[19];
    const float* b2     = (const float*)d_in[20];
    float* out = (float*)d_out;

    char* p = (char*)d_ws;
    auto alloc = [&](size_t bytes) -> char* {
        char* r = p;
        p += (bytes + 255) & ~(size_t)255;
        return r;
    };
    u16*   FS16     = (u16*)alloc((size_t)N_NODES * F2 * 2);
    u16*   FD16     = (u16*)alloc((size_t)N_NODES * F2 * 2);
    float* h1       = (float*)alloc((size_t)N_NODES * F2 * 4);
    float* gate     = (float*)alloc((size_t)N_NODES * 4);
    float* stats    = (float*)alloc(1024 * 4);
    float* bn_scale = (float*)alloc(512 * 4);
    float* bn_shift = (float*)alloc(512 * 4);
    float* h_gnum   = (float*)alloc((size_t)N_GRAPH * HID * 4);
    float* gden     = (float*)alloc((size_t)N_GRAPH * 4);
    int* counts     = (int*)alloc((size_t)N_NODES * 4);
    int* row_ptr    = (int*)alloc((size_t)(N_NODES + 1) * 4);
    int* cursor     = (int*)alloc((size_t)N_NODES * 4);
    int* csr_src    = (int*)alloc((size_t)N_EDGES * 4);
    int* bsum       = (int*)alloc((size_t)SCAN_BLOCKS * 4);
    u16* Fhi        = (u16*)alloc((size_t)N_NODES * IN_DIM * 2);  // aliased as hr later
    u16* Wthi       = (u16*)alloc((size_t)4 * 512 * 512 * 2);
    u16* Wtlo       = (u16*)alloc((size_t)4 * 512 * 512 * 2);
    // hr (20.48 MB) aliases Fhi (20.48 MB): Fhi's last use (input GEMMs)
    // strictly precedes hr's first write (reducer GEMM).
    float* hr = (float*)Fhi;
    (void)ws_size; (void)in_sizes; (void)n_in; (void)out_size;

    const size_t WSZ = (size_t)512 * 512;

    // 1. init + input conversions
    init_zero_kernel<<<(N_NODES + 255) / 256, 256, 0, stream>>>(counts, cursor, stats, h_gnum, gden);
    split_feat_kernel<<<(N_NODES * IN_DIM / 8 + 255) / 256, 256, 0, stream>>>(
        feat, Fhi, N_NODES * IN_DIM / 8);
    split_wt_kernel<<<dim3(16, 16, 4), dim3(32, 8), 0, stream>>>(
        W_src, W_dst, W_skip, W_red, Wthi, Wtlo);

    // 2. fused input GEMM triple (single launch, 1-term bf16)
    gemm_mfma_triple<<<dim3((N_NODES + 127) / 128, 12), 256, 0, stream>>>(
        Fhi, Wthi, b_src, b_dst, b_skip, FS16, FD16, h1);

    // 3-5. CSR by dst
    hist_kernel<<<(N_EDGES + 255) / 256, 256, 0, stream>>>(dst, counts);
    scan_local_kernel<<<SCAN_BLOCKS, 256, 0, stream>>>(counts, row_ptr, bsum);
    scan_fixup_kernel<<<SCAN_BLOCKS, 256, 0, stream>>>(bsum, row_ptr);
    scatter_kernel<<<(N_EDGES + 255) / 256, 256, 0, stream>>>(src, dst, row_ptr, cursor, csr_src);

    // 6. fused edge phase v4 (single pass)
    edge_fused_kernel<<<N_NODES, 256, 0, stream>>>(FS16, FD16, attn, csr_src, row_ptr, h1);

    // 7-8. BatchNorm stats -> scale/shift
    bn_stats_kernel<<<500, 256, 0, stream>>>(h1, stats, 40);
    bn_finalize_kernel<<<1, 512, 0, stream>>>(stats, gamma, beta, bn_scale, bn_shift);

    // 9. hr = BN(h1) @ W_red + b_red  (MFMA, 3-term, BN fold at staging)
    dim3 g256((N_NODES + 127) / 128, 2);
    gemm_mfma_red<<<g256, 256, 0, stream>>>(
        h1, Wthi + 3 * WSZ, Wtlo + 3 * WSZ, b_red, hr, N_NODES, HID,
        bn_scale, bn_shift);

    // 10. gate
    gate_kernel<<<N_NODES / 4, 256, 0, stream>>>(hr, w_gate, gate);

    // 11. per-graph pooling (8 partial blocks per graph)
    pool_partial_kernel<<<N_GRAPH * 8, 256, 0, stream>>>(hr, gate, gids, h_gnum, gden);

    // 12. classifier (+ pooling divide)
    classifier_kernel<<<N_GRAPH, 128, 0, stream>>>(h_gnum, gden, W1, b1, W2, b2, out);
}